// Round 2
// baseline (469.420 us; speedup 1.0000x reference)
//
#include <hip/hip_runtime.h>
#include <cstdint>
#include <cstddef>

#define NB 32        // batch
#define NC 256       // channels
#define HW 56        // spatial
#define PLANE (HW*HW)       // 3136
#define NPLANE (NB*NC)      // 8192
#define NHEADS 8
#define HDIM 32
#define NPOOL 64            // 8*8
#define EPSV 1e-5f
#define NBLK 1024
#define PPB (NPLANE/NBLK)   // 8 planes per block in streaming phases
#define NUM_CU 256

// LDS union kept <= 14.6 KB so 4 blocks/CU fit even under a 64 KB/CU calc.
struct Ph13 { float buf[PLANE]; float ha[56]; float wa[56]; };   // 12992 B
struct Ph2  { float rows[64*57]; float red[8]; };                // 14624 B (max)
struct Ph4  { float yn[32][65]; float G[32][33]; float ybar[32]; float red[8]; float stats[2]; };
struct Ph5  { float hv[8][56]; float wv[8][56]; };               // 3584 B
union SmemU { Ph13 a; Ph2 b; Ph4 c; Ph5 d; };

// ---- LLC-coherent (cross-XCD) scalar access for intermediates.
// Relaxed agent-scope atomics compile to sc0 sc1 loads/stores: they bypass the
// non-coherent per-XCD L2 and are served by the memory-side Infinity Cache.
// This makes the grid barrier fence-free (no buffer_wbl2 / buffer_inv storms).
__device__ __forceinline__ float cload(const float* p) {
    return __hip_atomic_load(p, __ATOMIC_RELAXED, __HIP_MEMORY_SCOPE_AGENT);
}
__device__ __forceinline__ void cstore(float* p, float v) {
    __hip_atomic_store(p, v, __ATOMIC_RELAXED, __HIP_MEMORY_SCOPE_AGENT);
}

// Fence-free grid barrier. Preconditions: all cross-block data moves via
// cload/cstore (LLC-coherent), counters zeroed before launch (hipMemsetAsync
// captured in the graph), all NBLK blocks resident (cooperative launch).
// __syncthreads drains vmcnt per wave, so every sc1 store is globally visible
// before the leader's arrive-add.
__device__ __forceinline__ void gbar(unsigned* c) {
    __syncthreads();
    if (threadIdx.x == 0) {
        __hip_atomic_fetch_add(c, 1u, __ATOMIC_RELAXED, __HIP_MEMORY_SCOPE_AGENT);
        while (__hip_atomic_load(c, __ATOMIC_RELAXED, __HIP_MEMORY_SCOPE_AGENT) < NBLK) {
            __builtin_amdgcn_s_sleep(1);
        }
        asm volatile("" ::: "memory");   // compiler-only fence; HW coherence via sc1
    }
    __syncthreads();
}

// ---- phase 2 worker: depthwise conv (uniform K per block) + GroupNorm(group==block) + sigmoid
template<int K>
__device__ __forceinline__ void ph2_work(const float* __restrict__ src,
                                         const float* __restrict__ wk,
                                         const float* __restrict__ bk,
                                         const float* __restrict__ scale,
                                         const float* __restrict__ bias,
                                         float* __restrict__ dst,
                                         int cbase, Ph2* S2, int t) {
#pragma unroll
    for (int k2 = 0; k2 < 4; ++k2) {
        int f = t + 256 * k2;
        if (f < 896) {
            int c = f / 14, r = f - c * 14;
            float* d = &S2->rows[c * 57 + r * 4];
            const float* s = src + f * 4;
            d[0] = cload(s); d[1] = cload(s + 1); d[2] = cload(s + 2); d[3] = cload(s + 3);
        }
    }
    __syncthreads();
    int cc = t >> 2, q = t & 3;          // channel-in-group, quarter
    float w[K];
#pragma unroll
    for (int j = 0; j < K; ++j) w[j] = wk[cc * K + j];
    float bb = bk[cc];
    const float* row = &S2->rows[cc * 57];
    float y[14];
    float s1 = 0.f, s2 = 0.f;
#pragma unroll
    for (int il = 0; il < 14; ++il) {
        int pos = q * 14 + il;
        float a = bb;
#pragma unroll
        for (int j = 0; j < K; ++j) {
            int p2 = pos + j - K / 2;
            if (p2 >= 0 && p2 < 56) a += w[j] * row[p2];
        }
        y[il] = a; s1 += a; s2 += a * a;
    }
#pragma unroll
    for (int off = 32; off >= 1; off >>= 1) {
        s1 += __shfl_xor(s1, off);
        s2 += __shfl_xor(s2, off);
    }
    int wv = t >> 6;
    if ((t & 63) == 0) { S2->red[wv] = s1; S2->red[4 + wv] = s2; }
    __syncthreads();
    float t1 = S2->red[0] + S2->red[1] + S2->red[2] + S2->red[3];
    float t2 = S2->red[4] + S2->red[5] + S2->red[6] + S2->red[7];
    float mean = t1 * (1.f / 3584.f);
    float var = t2 * (1.f / 3584.f) - mean * mean;
    float rstd = rsqrtf(var + EPSV);
    int c = cbase + cc;
    float scv = scale[c];
    float a_lin = scv * rstd, b_lin = bias[c] - mean * rstd * scv;
#pragma unroll
    for (int il = 0; il < 14; ++il) {
        float v = y[il] * a_lin + b_lin;
        S2->rows[cc * 57 + q * 14 + il] = 1.f / (1.f + expf(-v));
    }
    __syncthreads();
#pragma unroll
    for (int k2 = 0; k2 < 4; ++k2) {
        int f = t + 256 * k2;
        if (f < 896) {
            int c2 = f / 14, r = f - c2 * 14;
            const float* s = &S2->rows[c2 * 57 + r * 4];
            float* d = dst + f * 4;
            cstore(d, s[0]); cstore(d + 1, s[1]); cstore(d + 2, s[2]); cstore(d + 3, s[3]);
        }
    }
}

__global__ __launch_bounds__(256, 4) void k_mega(
    const float* __restrict__ x,
    const float* __restrict__ w3, const float* __restrict__ b3,
    const float* __restrict__ w5, const float* __restrict__ b5,
    const float* __restrict__ w7, const float* __restrict__ b7,
    const float* __restrict__ w9, const float* __restrict__ b9,
    const float* __restrict__ hsc, const float* __restrict__ hbi,
    const float* __restrict__ wsc, const float* __restrict__ wbi,
    const float* __restrict__ nsc, const float* __restrict__ nbi,
    const float* __restrict__ qw, const float* __restrict__ kw,
    const float* __restrict__ vw,
    float* __restrict__ hm, float* __restrict__ wm,
    float* __restrict__ hattn, float* __restrict__ wattn,
    float* __restrict__ ypool, float* __restrict__ ca,
    float* __restrict__ out, unsigned* __restrict__ bar)
{
    __shared__ SmemU S;
    const int t = threadIdx.x;
    const int bid = blockIdx.x;

    // ============ Phase 1: per-plane row/col means ============
    for (int p = 0; p < PPB; ++p) {
        int plane = bid * PPB + p;
        {
            const float4* xp = (const float4*)(x + (size_t)plane * PLANE);
            float4* smp = (float4*)S.a.buf;
            for (int f = t; f < PLANE / 4; f += 256) smp[f] = xp[f];
        }
        __syncthreads();
        const float* sm = S.a.buf;
        if (t < 224) {
            int a = t >> 2, q = t & 3;
            float s = 0.f;
#pragma unroll
            for (int i = 0; i < 14; ++i) s += sm[a * 56 + q * 14 + i];
            s += __shfl_xor(s, 1); s += __shfl_xor(s, 2);
            if (q == 0) cstore(&hm[(size_t)plane * 56 + a], s * (1.f / 56.f));
            float s2 = 0.f;
#pragma unroll
            for (int i = 0; i < 14; ++i) s2 += sm[(q * 14 + i) * 56 + a];
            s2 += __shfl_xor(s2, 1); s2 += __shfl_xor(s2, 2);
            if (q == 0) cstore(&wm[(size_t)plane * 56 + a], s2 * (1.f / 56.f));
        }
        __syncthreads();
    }
    gbar(bar + 0);

    // ============ Phase 2: sa_branch (conv + GN4 + sigmoid), 256 active blocks ============
    if (bid < 256) {
        int mode = bid & 1, b = (bid >> 1) & 31, g = bid >> 6;
        const float* src = (mode ? wm : hm) + ((size_t)b * NC + g * 64) * 56;
        float* dst = (mode ? wattn : hattn) + ((size_t)b * NC + g * 64) * 56;
        const float* scale = mode ? wsc : hsc;
        const float* bias = mode ? wbi : hbi;
        switch (g) {
            case 0: ph2_work<3>(src, w3, b3, scale, bias, dst, 0,   &S.b, t); break;
            case 1: ph2_work<5>(src, w5, b5, scale, bias, dst, 64,  &S.b, t); break;
            case 2: ph2_work<7>(src, w7, b7, scale, bias, dst, 128, &S.b, t); break;
            default: ph2_work<9>(src, w9, b9, scale, bias, dst, 192, &S.b, t); break;
        }
    }
    gbar(bar + 32);

    // ============ Phase 3: gated 7x7 avgpool -> ypool ============
    for (int p = 0; p < PPB; ++p) {
        int plane = bid * PPB + p;
        {
            const float4* xp = (const float4*)(x + (size_t)plane * PLANE);
            float4* smp = (float4*)S.a.buf;
            for (int f = t; f < PLANE / 4; f += 256) smp[f] = xp[f];
            if (t < 56) S.a.ha[t] = cload(&hattn[(size_t)plane * 56 + t]);
            else if (t >= 64 && t < 120) S.a.wa[t - 64] = cload(&wattn[(size_t)plane * 56 + (t - 64)]);
        }
        __syncthreads();
        {
            const float* sm = S.a.buf;
            const float* ha = S.a.ha;
            const float* wa = S.a.wa;
            int cell = t >> 2, sub = t & 3;
            int i = cell >> 3, j = cell & 7;
            float s = 0.f;
#pragma unroll
            for (int k2 = 0; k2 < 2; ++k2) {
                int dh = sub + 4 * k2;
                if (dh < 7) {
                    float r = 0.f;
#pragma unroll
                    for (int dw = 0; dw < 7; ++dw)
                        r += sm[(7 * i + dh) * 56 + 7 * j + dw] * wa[7 * j + dw];
                    s += ha[7 * i + dh] * r;
                }
            }
            s += __shfl_xor(s, 1); s += __shfl_xor(s, 2);
            if (sub == 0) cstore(&ypool[(size_t)plane * NPOOL + cell], s * (1.f / 49.f));
        }
        __syncthreads();
    }
    gbar(bar + 64);

    // ============ Phase 4: GN1 stats + attention -> ca, 256 active blocks ============
    if (bid < 256) {
        int b = bid >> 3, h = bid & 7;
        const float* bp = ypool + (size_t)b * NC * NPOOL;
        float s1 = 0.f, s2 = 0.f;
#pragma unroll
        for (int k2 = 0; k2 < 16; ++k2) {
            int i4 = (t + 256 * k2) * 4;
            float vx = cload(bp + i4), vy = cload(bp + i4 + 1);
            float vz = cload(bp + i4 + 2), vw2 = cload(bp + i4 + 3);
            s1 += vx + vy + vz + vw2;
            s2 += vx * vx + vy * vy + vz * vz + vw2 * vw2;
        }
#pragma unroll
        for (int off = 32; off >= 1; off >>= 1) {
            s1 += __shfl_xor(s1, off);
            s2 += __shfl_xor(s2, off);
        }
        if ((t & 63) == 0) { S.c.red[t >> 6] = s1; S.c.red[4 + (t >> 6)] = s2; }
        __syncthreads();
        if (t == 0) {
            float t1 = S.c.red[0] + S.c.red[1] + S.c.red[2] + S.c.red[3];
            float t2 = S.c.red[4] + S.c.red[5] + S.c.red[6] + S.c.red[7];
            float mean = t1 * (1.f / (NC * NPOOL));
            float var = t2 * (1.f / (NC * NPOOL)) - mean * mean;
            S.c.stats[0] = mean; S.c.stats[1] = rsqrtf(var + EPSV);
        }
        __syncthreads();
        float mean = S.c.stats[0], rstd = S.c.stats[1];
        const float* base = ypool + ((size_t)b * NC + h * HDIM) * NPOOL;
#pragma unroll
        for (int m = 0; m < 8; ++m) {
            int idx = t + 256 * m;
            int d = idx >> 6, p = idx & 63;
            int ch = h * HDIM + d;
            S.c.yn[d][p] = (cload(&base[idx]) - mean) * rstd * nsc[ch] + nbi[ch];
        }
        __syncthreads();
        if (t < 32) {
            float s = 0.f;
#pragma unroll
            for (int p = 0; p < 64; ++p) s += S.c.yn[t][p];
            S.c.ybar[t] = s * (1.f / 64.f);
        }
        __syncthreads();
#pragma unroll
        for (int m = 0; m < 4; ++m) {
            int idx = t + 256 * m;
            int d = idx >> 5, e = idx & 31;
            float s = 0.f;
#pragma unroll
            for (int p = 0; p < 64; ++p) s += S.c.yn[d][p] * S.c.yn[e][p];
            S.c.G[d][e] = s;
        }
        __syncthreads();
        if (t < 32) {
            int d = t, cd = h * HDIM + d;
            float qs = qw[cd] * 0.17677669529663687f;  // 1/sqrt(32)
            float a[32];
            float mx = -1e30f;
#pragma unroll
            for (int e = 0; e < 32; ++e) {
                a[e] = S.c.G[d][e] * qs * kw[h * HDIM + e];
                mx = fmaxf(mx, a[e]);
            }
            float sum = 0.f;
#pragma unroll
            for (int e = 0; e < 32; ++e) {
                a[e] = expf(a[e] - mx);
                sum += a[e];
            }
            float o = 0.f;
#pragma unroll
            for (int e = 0; e < 32; ++e) o += a[e] * vw[h * HDIM + e] * S.c.ybar[e];
            o /= sum;
            cstore(&ca[b * NC + cd], 1.f / (1.f + expf(-o)));
        }
    }
    gbar(bar + 96);

    // ============ Phase 5: out = x * hattn * wattn * ca (gates preloaded, barrier-free stream) ============
    {
        for (int i = t; i < 448; i += 256) {
            int p = i / 56, a = i - p * 56;
            int pl = bid * PPB + p;
            S.d.hv[p][a] = cload(&hattn[(size_t)pl * 56 + a]) * cload(&ca[pl]);
            S.d.wv[p][a] = cload(&wattn[(size_t)pl * 56 + a]);
        }
        __syncthreads();
        for (int p = 0; p < PPB; ++p) {
            int plane = bid * PPB + p;
            const float* hv = S.d.hv[p];
            const float* wv = S.d.wv[p];
            const float4* xp = (const float4*)(x + (size_t)plane * PLANE);
            float4* op = (float4*)(out + (size_t)plane * PLANE);
            for (int f = t; f < PLANE / 4; f += 256) {
                int r = f / 14, s0 = (f - r * 14) * 4;
                float4 v = xp[f];
                float hf = hv[r];
                v.x *= hf * wv[s0];
                v.y *= hf * wv[s0 + 1];
                v.z *= hf * wv[s0 + 2];
                v.w *= hf * wv[s0 + 3];
                op[f] = v;
            }
        }
    }
}

// ======================= Fallback path (round-2, known-good) =======================
__global__ __launch_bounds__(256) void k_means(const float* __restrict__ x,
                                               float* __restrict__ hm,
                                               float* __restrict__ wm) {
    int plane = blockIdx.x;
    __shared__ float sm[PLANE];
    const float4* xp = (const float4*)(x + (size_t)plane * PLANE);
    float4* smp = (float4*)sm;
    int t = threadIdx.x;
    for (int f = t; f < PLANE / 4; f += 256) smp[f] = xp[f];
    __syncthreads();
    if (t < 224) {
        int a = t >> 2, q = t & 3;
        float s = 0.f;
#pragma unroll
        for (int i = 0; i < 14; ++i) s += sm[a * 56 + q * 14 + i];
        s += __shfl_xor(s, 1); s += __shfl_xor(s, 2);
        if (q == 0) hm[(size_t)plane * 56 + a] = s * (1.f / 56.f);
        float s2 = 0.f;
#pragma unroll
        for (int i = 0; i < 14; ++i) s2 += sm[(q * 14 + i) * 56 + a];
        s2 += __shfl_xor(s2, 1); s2 += __shfl_xor(s2, 2);
        if (q == 0) wm[(size_t)plane * 56 + a] = s2 * (1.f / 56.f);
    }
}

__global__ __launch_bounds__(256) void k_branch(
    const float* __restrict__ hm, const float* __restrict__ wm,
    const float* __restrict__ w3, const float* __restrict__ b3,
    const float* __restrict__ w5, const float* __restrict__ b5,
    const float* __restrict__ w7, const float* __restrict__ b7,
    const float* __restrict__ w9, const float* __restrict__ b9,
    const float* __restrict__ hsc, const float* __restrict__ hbi,
    const float* __restrict__ wsc, const float* __restrict__ wbi,
    float* __restrict__ hattn, float* __restrict__ wattn) {
    int mode = blockIdx.x & 1;
    int b = blockIdx.x >> 1;
    const float* src = (mode == 0 ? hm : wm) + (size_t)b * NC * 56;
    const float* scale = (mode == 0 ? hsc : wsc);
    const float* bias = (mode == 0 ? hbi : wbi);
    float* dst = (mode == 0 ? hattn : wattn) + (size_t)b * NC * 56;

    __shared__ float sm[NC * 57];
    int t = threadIdx.x;
    const float4* sp = (const float4*)src;
#pragma unroll
    for (int k = 0; k < 14; ++k) {
        int f = t + 256 * k;
        float4 v = sp[f];
        int c = f / 14, r = f - c * 14;
        float* d = &sm[c * 57 + r * 4];
        d[0] = v.x; d[1] = v.y; d[2] = v.z; d[3] = v.w;
    }
    __syncthreads();

    int c = t;
    int g = c >> 6, cc = c & 63;
    float wc[9];
#pragma unroll
    for (int i = 0; i < 9; ++i) wc[i] = 0.f;
    float bb = 0.f;
    if (g == 0) {
#pragma unroll
        for (int q = 0; q < 3; ++q) wc[3 + q] = w3[cc * 3 + q];
        bb = b3[cc];
    } else if (g == 1) {
#pragma unroll
        for (int q = 0; q < 5; ++q) wc[2 + q] = w5[cc * 5 + q];
        bb = b5[cc];
    } else if (g == 2) {
#pragma unroll
        for (int q = 0; q < 7; ++q) wc[1 + q] = w7[cc * 7 + q];
        bb = b7[cc];
    } else {
#pragma unroll
        for (int q = 0; q < 9; ++q) wc[q] = w9[cc * 9 + q];
        bb = b9[cc];
    }

    float xv[56];
#pragma unroll
    for (int i = 0; i < 56; ++i) xv[i] = sm[c * 57 + i];

    float s1 = 0.f, s2 = 0.f;
#pragma unroll
    for (int i = 0; i < 56; ++i) {
        float a = bb;
#pragma unroll
        for (int d = 0; d < 9; ++d) {
            int j = i + d - 4;
            if (j >= 0 && j < 56) a += wc[d] * xv[j];
        }
        s1 += a;
        s2 += a * a;
    }
#pragma unroll
    for (int off = 32; off >= 1; off >>= 1) {
        s1 += __shfl_xor(s1, off);
        s2 += __shfl_xor(s2, off);
    }
    float mean = s1 * (1.f / 3584.f);
    float var = s2 * (1.f / 3584.f) - mean * mean;
    float rstd = rsqrtf(var + EPSV);
    float scv = scale[c];
    float a_lin = scv * rstd;
    float b_lin = bias[c] - mean * rstd * scv;
#pragma unroll
    for (int i = 0; i < 56; ++i) {
        float a = bb;
#pragma unroll
        for (int d = 0; d < 9; ++d) {
            int j = i + d - 4;
            if (j >= 0 && j < 56) a += wc[d] * xv[j];
        }
        float v = a * a_lin + b_lin;
        sm[c * 57 + i] = 1.f / (1.f + expf(-v));
    }
    __syncthreads();
    float4* dp = (float4*)dst;
#pragma unroll
    for (int k = 0; k < 14; ++k) {
        int f = t + 256 * k;
        int c2 = f / 14, r = f - c2 * 14;
        const float* s = &sm[c2 * 57 + r * 4];
        dp[f] = make_float4(s[0], s[1], s[2], s[3]);
    }
}

__global__ __launch_bounds__(256) void k_pool(const float* __restrict__ x,
                                              const float* __restrict__ hattn,
                                              const float* __restrict__ wattn,
                                              float* __restrict__ ypool) {
    int plane = blockIdx.x;
    __shared__ float sm[PLANE];
    __shared__ float ha[56], wa[56];
    const float4* xp = (const float4*)(x + (size_t)plane * PLANE);
    float4* smp = (float4*)sm;
    int t = threadIdx.x;
    for (int f = t; f < PLANE / 4; f += 256) smp[f] = xp[f];
    if (t < 56) ha[t] = hattn[(size_t)plane * 56 + t];
    else if (t >= 64 && t < 120) wa[t - 64] = wattn[(size_t)plane * 56 + (t - 64)];
    __syncthreads();
    if (t < 64) {
        int i = t >> 3, j = t & 7;
        float s = 0.f;
#pragma unroll
        for (int dh = 0; dh < 7; ++dh) {
            float hv = ha[7 * i + dh];
            float r = 0.f;
#pragma unroll
            for (int dw = 0; dw < 7; ++dw)
                r += sm[(7 * i + dh) * 56 + 7 * j + dw] * wa[7 * j + dw];
            s += hv * r;
        }
        ypool[(size_t)plane * NPOOL + t] = s * (1.f / 49.f);
    }
}

__global__ __launch_bounds__(64) void k_attn(const float* __restrict__ ypool,
                                             const float* __restrict__ nsc,
                                             const float* __restrict__ nbi,
                                             const float* __restrict__ qw,
                                             const float* __restrict__ kw,
                                             const float* __restrict__ vw,
                                             float* __restrict__ ca) {
    int bh = blockIdx.x;
    int b = bh >> 3, h = bh & 7;
    int l = threadIdx.x;
    const float4* bp = (const float4*)(ypool + (size_t)b * NC * NPOOL);
    float s1 = 0.f, s2 = 0.f;
#pragma unroll
    for (int k = 0; k < 64; ++k) {
        float4 v = bp[l + 64 * k];
        s1 += v.x + v.y + v.z + v.w;
        s2 += v.x * v.x + v.y * v.y + v.z * v.z + v.w * v.w;
    }
#pragma unroll
    for (int off = 32; off >= 1; off >>= 1) {
        s1 += __shfl_xor(s1, off);
        s2 += __shfl_xor(s2, off);
    }
    float mean = s1 * (1.f / (NC * NPOOL));
    float var = s2 * (1.f / (NC * NPOOL)) - mean * mean;
    float rstd = rsqrtf(var + EPSV);

    __shared__ float yn[32][65];
    __shared__ float ybar[32];
    __shared__ float G[32][33];
    const float* base = ypool + ((size_t)b * NC + h * HDIM) * NPOOL;
#pragma unroll
    for (int m = 0; m < 32; ++m) {
        int idx = l + 64 * m;
        int d = idx >> 6, p = idx & 63;
        int ch = h * HDIM + d;
        float v = base[idx];
        yn[d][p] = (v - mean) * rstd * nsc[ch] + nbi[ch];
    }
    __syncthreads();
    if (l < 32) {
        float s = 0.f;
#pragma unroll
        for (int p = 0; p < 64; ++p) s += yn[l][p];
        ybar[l] = s * (1.f / 64.f);
    }
    __syncthreads();
#pragma unroll
    for (int m = 0; m < 16; ++m) {
        int idx = l + 64 * m;
        int d = idx >> 5, e = idx & 31;
        float s = 0.f;
#pragma unroll
        for (int p = 0; p < 64; ++p) s += yn[d][p] * yn[e][p];
        G[d][e] = s;
    }
    __syncthreads();
    if (l < 32) {
        int d = l, cd = h * HDIM + d;
        float qs = qw[cd] * 0.17677669529663687f;
        float a[32];
        float mx = -1e30f;
#pragma unroll
        for (int e = 0; e < 32; ++e) {
            a[e] = G[d][e] * qs * kw[h * HDIM + e];
            mx = fmaxf(mx, a[e]);
        }
        float sum = 0.f;
#pragma unroll
        for (int e = 0; e < 32; ++e) {
            a[e] = expf(a[e] - mx);
            sum += a[e];
        }
        float o = 0.f;
#pragma unroll
        for (int e = 0; e < 32; ++e) o += a[e] * vw[h * HDIM + e] * ybar[e];
        o /= sum;
        ca[b * NC + cd] = 1.f / (1.f + expf(-o));
    }
}

__global__ __launch_bounds__(256) void k_final(const float* __restrict__ x,
                                               const float* __restrict__ hattn,
                                               const float* __restrict__ wattn,
                                               const float* __restrict__ ca,
                                               float* __restrict__ out) {
    int plane = blockIdx.x;
    __shared__ float hv[56], wv[56];
    int t = threadIdx.x;
    float cav = ca[plane];
    if (t < 56) hv[t] = hattn[(size_t)plane * 56 + t] * cav;
    else if (t >= 64 && t < 120) wv[t - 64] = wattn[(size_t)plane * 56 + (t - 64)];
    __syncthreads();
    const float4* xp = (const float4*)(x + (size_t)plane * PLANE);
    float4* op = (float4*)(out + (size_t)plane * PLANE);
    for (int f = t; f < PLANE / 4; f += 256) {
        int r = f / 14;
        int s0 = (f - r * 14) * 4;
        float4 v = xp[f];
        float hf = hv[r];
        v.x *= hf * wv[s0];
        v.y *= hf * wv[s0 + 1];
        v.z *= hf * wv[s0 + 2];
        v.w *= hf * wv[s0 + 3];
        op[f] = v;
    }
}

extern "C" void kernel_launch(void* const* d_in, const int* in_sizes, int n_in,
                              void* d_out, int out_size, void* d_ws, size_t ws_size,
                              hipStream_t stream) {
    const float* x   = (const float*)d_in[0];
    const float* w3  = (const float*)d_in[1];
    const float* b3  = (const float*)d_in[2];
    const float* w5  = (const float*)d_in[3];
    const float* b5  = (const float*)d_in[4];
    const float* w7  = (const float*)d_in[5];
    const float* b7  = (const float*)d_in[6];
    const float* w9  = (const float*)d_in[7];
    const float* b9  = (const float*)d_in[8];
    const float* hsc = (const float*)d_in[9];
    const float* hbi = (const float*)d_in[10];
    const float* wsc = (const float*)d_in[11];
    const float* wbi = (const float*)d_in[12];
    const float* nsc = (const float*)d_in[13];
    const float* nbi = (const float*)d_in[14];
    const float* qw  = (const float*)d_in[15];
    const float* kw  = (const float*)d_in[16];
    const float* vw  = (const float*)d_in[17];
    float* out = (float*)d_out;

    float* ws    = (float*)d_ws;
    float* hm    = ws;
    float* wm    = hm + (size_t)NPLANE * 56;
    float* hattn = wm + (size_t)NPLANE * 56;
    float* wattn = hattn + (size_t)NPLANE * 56;
    float* ypool = wattn + (size_t)NPLANE * 56;
    float* ca    = ypool + (size_t)NPLANE * NPOOL;
    unsigned* bar = (unsigned*)(ca + (size_t)NB * NC);

    // Try cooperative mega-kernel; fall back to the proven 5-kernel path.
    bool coop_done = false;
    int maxb = 0;
    hipError_t qe = hipOccupancyMaxActiveBlocksPerMultiprocessor(
        &maxb, (const void*)k_mega, 256, 0);
    if (qe == hipSuccess && maxb * NUM_CU >= NBLK) {
        // Zero the barrier counters (captured into the graph -> reset each replay).
        (void)hipMemsetAsync(bar, 0, 128 * sizeof(unsigned), stream);
        void* args[] = {
            (void*)&x,
            (void*)&w3, (void*)&b3, (void*)&w5, (void*)&b5,
            (void*)&w7, (void*)&b7, (void*)&w9, (void*)&b9,
            (void*)&hsc, (void*)&hbi, (void*)&wsc, (void*)&wbi,
            (void*)&nsc, (void*)&nbi,
            (void*)&qw, (void*)&kw, (void*)&vw,
            (void*)&hm, (void*)&wm, (void*)&hattn, (void*)&wattn,
            (void*)&ypool, (void*)&ca, (void*)&out, (void*)&bar
        };
        hipError_t le = hipLaunchCooperativeKernel((const void*)k_mega, dim3(NBLK),
                                                   dim3(256), args, 0, stream);
        coop_done = (le == hipSuccess);
    }
    if (!coop_done) {
        (void)hipGetLastError();  // clear any sticky error from the rejected launch
        k_means<<<NPLANE, 256, 0, stream>>>(x, hm, wm);
        k_branch<<<2 * NB, 256, 0, stream>>>(hm, wm, w3, b3, w5, b5, w7, b7, w9, b9,
                                             hsc, hbi, wsc, wbi, hattn, wattn);
        k_pool<<<NPLANE, 256, 0, stream>>>(x, hattn, wattn, ypool);
        k_attn<<<NB * NHEADS, 64, 0, stream>>>(ypool, nsc, nbi, qw, kw, vw, ca);
        k_final<<<NPLANE, 256, 0, stream>>>(x, hattn, wattn, ca, out);
    }
}

// Round 3
// 400.499 us; speedup vs baseline: 1.1721x; 1.1721x over previous
//
#include <hip/hip_runtime.h>
#include <cstdint>
#include <cstddef>

#define NB 32        // batch
#define NC 256       // channels
#define HW 56        // spatial
#define PLANE (HW*HW)       // 3136
#define NPLANE (NB*NC)      // 8192
#define NHEADS 8
#define HDIM 32
#define NPOOL 64            // 8*8
#define EPSV 1e-5f
#define NBLK 1024
#define PPB (NPLANE/NBLK)   // 8 planes per block in streaming phases
#define NUM_CU 256

// LDS union kept <= 14.6 KB so 4 blocks/CU fit even under a 64 KB/CU calc.
struct Ph13 { float buf[PLANE]; float ha[56]; float wa[56]; };   // 12992 B
struct Ph2  { float rows[64*57]; float red[8]; };                // 14624 B (max)
struct Ph4  { float yn[32][65]; float G[32][33]; float ybar[32]; float red[8]; float stats[2]; };
struct Ph5  { float hv[8][56]; float wv[8][56]; };               // 3584 B
union SmemU { Ph13 a; Ph2 b; Ph4 c; Ph5 d; };

// ---- LLC-coherent (cross-XCD) scalar access for intermediates.
// Relaxed agent-scope atomics compile to sc0 sc1 loads/stores: they bypass the
// non-coherent per-XCD L2 and are served by the memory-side Infinity Cache.
__device__ __forceinline__ float cload(const float* p) {
    return __hip_atomic_load(p, __ATOMIC_RELAXED, __HIP_MEMORY_SCOPE_AGENT);
}
__device__ __forceinline__ void cstore(float* p, float v) {
    __hip_atomic_store(p, v, __ATOMIC_RELAXED, __HIP_MEMORY_SCOPE_AGENT);
}

// ---- per-batch pipeline flags (no grid-wide barrier).
// arrive: __syncthreads drains each wave's sc1 stores (vmcnt) before the
// leader's LLC fetch_add, so counter==target implies producer data visible.
__device__ __forceinline__ void arrive_flag(unsigned* c) {
    __syncthreads();
    if (threadIdx.x == 0)
        __hip_atomic_fetch_add(c, 1u, __ATOMIC_RELAXED, __HIP_MEMORY_SCOPE_AGENT);
}
__device__ __forceinline__ void wait_flag(const unsigned* c, unsigned tgt) {
    if (threadIdx.x == 0) {
        while (__hip_atomic_load(c, __ATOMIC_RELAXED, __HIP_MEMORY_SCOPE_AGENT) < tgt) {
            __builtin_amdgcn_s_sleep(2);
        }
        asm volatile("" ::: "memory");   // compiler-only fence; HW coherence via sc1
    }
    __syncthreads();
}

// ---- phase 2 worker: depthwise conv (uniform K per block) + GroupNorm(group==block) + sigmoid
template<int K>
__device__ __forceinline__ void ph2_work(const float* __restrict__ src,
                                         const float* __restrict__ wk,
                                         const float* __restrict__ bk,
                                         const float* __restrict__ scale,
                                         const float* __restrict__ bias,
                                         float* __restrict__ dst,
                                         int cbase, Ph2* S2, int t) {
#pragma unroll
    for (int k2 = 0; k2 < 4; ++k2) {
        int f = t + 256 * k2;
        if (f < 896) {
            int c = f / 14, r = f - c * 14;
            float* d = &S2->rows[c * 57 + r * 4];
            const float* s = src + f * 4;
            d[0] = cload(s); d[1] = cload(s + 1); d[2] = cload(s + 2); d[3] = cload(s + 3);
        }
    }
    __syncthreads();
    int cc = t >> 2, q = t & 3;          // channel-in-group, quarter
    float w[K];
#pragma unroll
    for (int j = 0; j < K; ++j) w[j] = wk[cc * K + j];
    float bb = bk[cc];
    const float* row = &S2->rows[cc * 57];
    float y[14];
    float s1 = 0.f, s2 = 0.f;
#pragma unroll
    for (int il = 0; il < 14; ++il) {
        int pos = q * 14 + il;
        float a = bb;
#pragma unroll
        for (int j = 0; j < K; ++j) {
            int p2 = pos + j - K / 2;
            if (p2 >= 0 && p2 < 56) a += w[j] * row[p2];
        }
        y[il] = a; s1 += a; s2 += a * a;
    }
#pragma unroll
    for (int off = 32; off >= 1; off >>= 1) {
        s1 += __shfl_xor(s1, off);
        s2 += __shfl_xor(s2, off);
    }
    int wv = t >> 6;
    if ((t & 63) == 0) { S2->red[wv] = s1; S2->red[4 + wv] = s2; }
    __syncthreads();
    float t1 = S2->red[0] + S2->red[1] + S2->red[2] + S2->red[3];
    float t2 = S2->red[4] + S2->red[5] + S2->red[6] + S2->red[7];
    float mean = t1 * (1.f / 3584.f);
    float var = t2 * (1.f / 3584.f) - mean * mean;
    float rstd = rsqrtf(var + EPSV);
    int c = cbase + cc;
    float scv = scale[c];
    float a_lin = scv * rstd, b_lin = bias[c] - mean * rstd * scv;
#pragma unroll
    for (int il = 0; il < 14; ++il) {
        float v = y[il] * a_lin + b_lin;
        S2->rows[cc * 57 + q * 14 + il] = 1.f / (1.f + expf(-v));
    }
    __syncthreads();
#pragma unroll
    for (int k2 = 0; k2 < 4; ++k2) {
        int f = t + 256 * k2;
        if (f < 896) {
            int c2 = f / 14, r = f - c2 * 14;
            const float* s = &S2->rows[c2 * 57 + r * 4];
            float* d = dst + f * 4;
            cstore(d, s[0]); cstore(d + 1, s[1]); cstore(d + 2, s[2]); cstore(d + 3, s[3]);
        }
    }
}

// Per-batch pipelined mega-kernel. Block bid serves batch b = bid>>5 through
// all phases (rank r = bid&31). Stage completion tracked by per-batch LLC
// counters: c1[b]=32 (means), c2[b]=8 (gates), c3[b]=32 (pool), c4[b]=8 (ca).
// No grid-wide sync: batches pipeline independently; a straggler only delays
// its own batch. Plane->block mapping identical in P1/P3/P5, and the block is
// CU-resident for the whole launch, so P3/P5's x re-reads hit the same XCD L2.
__global__ __launch_bounds__(256, 4) void k_mega(
    const float* __restrict__ x,
    const float* __restrict__ w3, const float* __restrict__ b3,
    const float* __restrict__ w5, const float* __restrict__ b5,
    const float* __restrict__ w7, const float* __restrict__ b7,
    const float* __restrict__ w9, const float* __restrict__ b9,
    const float* __restrict__ hsc, const float* __restrict__ hbi,
    const float* __restrict__ wsc, const float* __restrict__ wbi,
    const float* __restrict__ nsc, const float* __restrict__ nbi,
    const float* __restrict__ qw, const float* __restrict__ kw,
    const float* __restrict__ vw,
    float* __restrict__ hm, float* __restrict__ wm,
    float* __restrict__ hattn, float* __restrict__ wattn,
    float* __restrict__ ypool, float* __restrict__ ca,
    float* __restrict__ out, unsigned* __restrict__ bar)
{
    __shared__ SmemU S;
    const int t = threadIdx.x;
    const int bid = blockIdx.x;
    const int b = bid >> 5;      // batch this block serves for its whole life
    const int r = bid & 31;      // rank within the batch's 32 blocks
    unsigned* c1 = bar;          // P1 done   (target 32)
    unsigned* c2 = bar + 32;     // P2 done   (target 8)
    unsigned* c3 = bar + 64;     // P3 done   (target 32)
    unsigned* c4 = bar + 96;     // P4 done   (target 8)

    // ============ Phase 1: per-plane row/col means (8 planes: bid*8+p) ============
    for (int p = 0; p < PPB; ++p) {
        int plane = bid * PPB + p;
        {
            const float4* xp = (const float4*)(x + (size_t)plane * PLANE);
            float4* smp = (float4*)S.a.buf;
            for (int f = t; f < PLANE / 4; f += 256) smp[f] = xp[f];
        }
        __syncthreads();
        const float* sm = S.a.buf;
        if (t < 224) {
            int a = t >> 2, q = t & 3;
            float s = 0.f;
#pragma unroll
            for (int i = 0; i < 14; ++i) s += sm[a * 56 + q * 14 + i];
            s += __shfl_xor(s, 1); s += __shfl_xor(s, 2);
            if (q == 0) cstore(&hm[(size_t)plane * 56 + a], s * (1.f / 56.f));
            float s2 = 0.f;
#pragma unroll
            for (int i = 0; i < 14; ++i) s2 += sm[(q * 14 + i) * 56 + a];
            s2 += __shfl_xor(s2, 1); s2 += __shfl_xor(s2, 2);
            if (q == 0) cstore(&wm[(size_t)plane * 56 + a], s2 * (1.f / 56.f));
        }
        __syncthreads();
    }
    arrive_flag(c1 + b);

    // ============ Phase 2: sa_branch (conv + GN4 + sigmoid), 8 jobs/batch ============
    if (r < 8) {
        wait_flag(c1 + b, 32);
        int mode = r & 1, g = r >> 1;
        const float* src = (mode ? wm : hm) + ((size_t)b * NC + g * 64) * 56;
        float* dst = (mode ? wattn : hattn) + ((size_t)b * NC + g * 64) * 56;
        const float* scale = mode ? wsc : hsc;
        const float* bias = mode ? wbi : hbi;
        switch (g) {
            case 0: ph2_work<3>(src, w3, b3, scale, bias, dst, 0,   &S.b, t); break;
            case 1: ph2_work<5>(src, w5, b5, scale, bias, dst, 64,  &S.b, t); break;
            case 2: ph2_work<7>(src, w7, b7, scale, bias, dst, 128, &S.b, t); break;
            default: ph2_work<9>(src, w9, b9, scale, bias, dst, 192, &S.b, t); break;
        }
        arrive_flag(c2 + b);
    }

    // ============ Phase 3: gated 7x7 avgpool -> ypool ============
    wait_flag(c2 + b, 8);
    for (int p = 0; p < PPB; ++p) {
        int plane = bid * PPB + p;
        {
            const float4* xp = (const float4*)(x + (size_t)plane * PLANE);
            float4* smp = (float4*)S.a.buf;
            for (int f = t; f < PLANE / 4; f += 256) smp[f] = xp[f];
            if (t < 56) S.a.ha[t] = cload(&hattn[(size_t)plane * 56 + t]);
            else if (t >= 64 && t < 120) S.a.wa[t - 64] = cload(&wattn[(size_t)plane * 56 + (t - 64)]);
        }
        __syncthreads();
        {
            const float* sm = S.a.buf;
            const float* ha = S.a.ha;
            const float* wa = S.a.wa;
            int cell = t >> 2, sub = t & 3;
            int i = cell >> 3, j = cell & 7;
            float s = 0.f;
#pragma unroll
            for (int k2 = 0; k2 < 2; ++k2) {
                int dh = sub + 4 * k2;
                if (dh < 7) {
                    float rr = 0.f;
#pragma unroll
                    for (int dw = 0; dw < 7; ++dw)
                        rr += sm[(7 * i + dh) * 56 + 7 * j + dw] * wa[7 * j + dw];
                    s += ha[7 * i + dh] * rr;
                }
            }
            s += __shfl_xor(s, 1); s += __shfl_xor(s, 2);
            if (sub == 0) cstore(&ypool[(size_t)plane * NPOOL + cell], s * (1.f / 49.f));
        }
        __syncthreads();
    }
    arrive_flag(c3 + b);

    // ============ Phase 4: GN1 stats + attention -> ca, 8 jobs/batch ============
    if (r < 8) {
        wait_flag(c3 + b, 32);
        int h = r;
        const float* bp = ypool + (size_t)b * NC * NPOOL;
        float s1 = 0.f, s2 = 0.f;
#pragma unroll
        for (int k2 = 0; k2 < 16; ++k2) {
            int i4 = (t + 256 * k2) * 4;
            float vx = cload(bp + i4), vy = cload(bp + i4 + 1);
            float vz = cload(bp + i4 + 2), vw2 = cload(bp + i4 + 3);
            s1 += vx + vy + vz + vw2;
            s2 += vx * vx + vy * vy + vz * vz + vw2 * vw2;
        }
#pragma unroll
        for (int off = 32; off >= 1; off >>= 1) {
            s1 += __shfl_xor(s1, off);
            s2 += __shfl_xor(s2, off);
        }
        if ((t & 63) == 0) { S.c.red[t >> 6] = s1; S.c.red[4 + (t >> 6)] = s2; }
        __syncthreads();
        if (t == 0) {
            float t1 = S.c.red[0] + S.c.red[1] + S.c.red[2] + S.c.red[3];
            float t2 = S.c.red[4] + S.c.red[5] + S.c.red[6] + S.c.red[7];
            float mean = t1 * (1.f / (NC * NPOOL));
            float var = t2 * (1.f / (NC * NPOOL)) - mean * mean;
            S.c.stats[0] = mean; S.c.stats[1] = rsqrtf(var + EPSV);
        }
        __syncthreads();
        float mean = S.c.stats[0], rstd = S.c.stats[1];
        const float* base = ypool + ((size_t)b * NC + h * HDIM) * NPOOL;
#pragma unroll
        for (int m = 0; m < 8; ++m) {
            int idx = t + 256 * m;
            int d = idx >> 6, p = idx & 63;
            int ch = h * HDIM + d;
            S.c.yn[d][p] = (cload(&base[idx]) - mean) * rstd * nsc[ch] + nbi[ch];
        }
        __syncthreads();
        if (t < 32) {
            float s = 0.f;
#pragma unroll
            for (int p = 0; p < 64; ++p) s += S.c.yn[t][p];
            S.c.ybar[t] = s * (1.f / 64.f);
        }
        __syncthreads();
#pragma unroll
        for (int m = 0; m < 4; ++m) {
            int idx = t + 256 * m;
            int d = idx >> 5, e = idx & 31;
            float s = 0.f;
#pragma unroll
            for (int p = 0; p < 64; ++p) s += S.c.yn[d][p] * S.c.yn[e][p];
            S.c.G[d][e] = s;
        }
        __syncthreads();
        if (t < 32) {
            int d = t, cd = h * HDIM + d;
            float qs = qw[cd] * 0.17677669529663687f;  // 1/sqrt(32)
            float a[32];
            float mx = -1e30f;
#pragma unroll
            for (int e = 0; e < 32; ++e) {
                a[e] = S.c.G[d][e] * qs * kw[h * HDIM + e];
                mx = fmaxf(mx, a[e]);
            }
            float sum = 0.f;
#pragma unroll
            for (int e = 0; e < 32; ++e) {
                a[e] = expf(a[e] - mx);
                sum += a[e];
            }
            float o = 0.f;
#pragma unroll
            for (int e = 0; e < 32; ++e) o += a[e] * vw[h * HDIM + e] * S.c.ybar[e];
            o /= sum;
            cstore(&ca[b * NC + cd], 1.f / (1.f + expf(-o)));
        }
        arrive_flag(c4 + b);
    }

    // ============ Phase 5: out = x * hattn * wattn * ca ============
    wait_flag(c4 + b, 8);
    {
        for (int i = t; i < 448; i += 256) {
            int p = i / 56, a = i - p * 56;
            int pl = bid * PPB + p;
            S.d.hv[p][a] = cload(&hattn[(size_t)pl * 56 + a]) * cload(&ca[pl]);
            S.d.wv[p][a] = cload(&wattn[(size_t)pl * 56 + a]);
        }
        __syncthreads();
        for (int p = 0; p < PPB; ++p) {
            int plane = bid * PPB + p;
            const float* hv = S.d.hv[p];
            const float* wv = S.d.wv[p];
            const float4* xp = (const float4*)(x + (size_t)plane * PLANE);
            float4* op = (float4*)(out + (size_t)plane * PLANE);
            for (int f = t; f < PLANE / 4; f += 256) {
                int rr = f / 14, s0 = (f - rr * 14) * 4;
                float4 v = xp[f];
                float hf = hv[rr];
                v.x *= hf * wv[s0];
                v.y *= hf * wv[s0 + 1];
                v.z *= hf * wv[s0 + 2];
                v.w *= hf * wv[s0 + 3];
                op[f] = v;
            }
        }
    }
}

// ======================= Fallback path (round-2, known-good) =======================
__global__ __launch_bounds__(256) void k_means(const float* __restrict__ x,
                                               float* __restrict__ hm,
                                               float* __restrict__ wm) {
    int plane = blockIdx.x;
    __shared__ float sm[PLANE];
    const float4* xp = (const float4*)(x + (size_t)plane * PLANE);
    float4* smp = (float4*)sm;
    int t = threadIdx.x;
    for (int f = t; f < PLANE / 4; f += 256) smp[f] = xp[f];
    __syncthreads();
    if (t < 224) {
        int a = t >> 2, q = t & 3;
        float s = 0.f;
#pragma unroll
        for (int i = 0; i < 14; ++i) s += sm[a * 56 + q * 14 + i];
        s += __shfl_xor(s, 1); s += __shfl_xor(s, 2);
        if (q == 0) hm[(size_t)plane * 56 + a] = s * (1.f / 56.f);
        float s2 = 0.f;
#pragma unroll
        for (int i = 0; i < 14; ++i) s2 += sm[(q * 14 + i) * 56 + a];
        s2 += __shfl_xor(s2, 1); s2 += __shfl_xor(s2, 2);
        if (q == 0) wm[(size_t)plane * 56 + a] = s2 * (1.f / 56.f);
    }
}

__global__ __launch_bounds__(256) void k_branch(
    const float* __restrict__ hm, const float* __restrict__ wm,
    const float* __restrict__ w3, const float* __restrict__ b3,
    const float* __restrict__ w5, const float* __restrict__ b5,
    const float* __restrict__ w7, const float* __restrict__ b7,
    const float* __restrict__ w9, const float* __restrict__ b9,
    const float* __restrict__ hsc, const float* __restrict__ hbi,
    const float* __restrict__ wsc, const float* __restrict__ wbi,
    float* __restrict__ hattn, float* __restrict__ wattn) {
    int mode = blockIdx.x & 1;
    int b = blockIdx.x >> 1;
    const float* src = (mode == 0 ? hm : wm) + (size_t)b * NC * 56;
    const float* scale = (mode == 0 ? hsc : wsc);
    const float* bias = (mode == 0 ? hbi : wbi);
    float* dst = (mode == 0 ? hattn : wattn) + (size_t)b * NC * 56;

    __shared__ float sm[NC * 57];
    int t = threadIdx.x;
    const float4* sp = (const float4*)src;
#pragma unroll
    for (int k = 0; k < 14; ++k) {
        int f = t + 256 * k;
        float4 v = sp[f];
        int c = f / 14, r = f - c * 14;
        float* d = &sm[c * 57 + r * 4];
        d[0] = v.x; d[1] = v.y; d[2] = v.z; d[3] = v.w;
    }
    __syncthreads();

    int c = t;
    int g = c >> 6, cc = c & 63;
    float wc[9];
#pragma unroll
    for (int i = 0; i < 9; ++i) wc[i] = 0.f;
    float bb = 0.f;
    if (g == 0) {
#pragma unroll
        for (int q = 0; q < 3; ++q) wc[3 + q] = w3[cc * 3 + q];
        bb = b3[cc];
    } else if (g == 1) {
#pragma unroll
        for (int q = 0; q < 5; ++q) wc[2 + q] = w5[cc * 5 + q];
        bb = b5[cc];
    } else if (g == 2) {
#pragma unroll
        for (int q = 0; q < 7; ++q) wc[1 + q] = w7[cc * 7 + q];
        bb = b7[cc];
    } else {
#pragma unroll
        for (int q = 0; q < 9; ++q) wc[q] = w9[cc * 9 + q];
        bb = b9[cc];
    }

    float xv[56];
#pragma unroll
    for (int i = 0; i < 56; ++i) xv[i] = sm[c * 57 + i];

    float s1 = 0.f, s2 = 0.f;
#pragma unroll
    for (int i = 0; i < 56; ++i) {
        float a = bb;
#pragma unroll
        for (int d = 0; d < 9; ++d) {
            int j = i + d - 4;
            if (j >= 0 && j < 56) a += wc[d] * xv[j];
        }
        s1 += a;
        s2 += a * a;
    }
#pragma unroll
    for (int off = 32; off >= 1; off >>= 1) {
        s1 += __shfl_xor(s1, off);
        s2 += __shfl_xor(s2, off);
    }
    float mean = s1 * (1.f / 3584.f);
    float var = s2 * (1.f / 3584.f) - mean * mean;
    float rstd = rsqrtf(var + EPSV);
    float scv = scale[c];
    float a_lin = scv * rstd;
    float b_lin = bias[c] - mean * rstd * scv;
#pragma unroll
    for (int i = 0; i < 56; ++i) {
        float a = bb;
#pragma unroll
        for (int d = 0; d < 9; ++d) {
            int j = i + d - 4;
            if (j >= 0 && j < 56) a += wc[d] * xv[j];
        }
        float v = a * a_lin + b_lin;
        sm[c * 57 + i] = 1.f / (1.f + expf(-v));
    }
    __syncthreads();
    float4* dp = (float4*)dst;
#pragma unroll
    for (int k = 0; k < 14; ++k) {
        int f = t + 256 * k;
        int c2 = f / 14, r = f - c2 * 14;
        const float* s = &sm[c2 * 57 + r * 4];
        dp[f] = make_float4(s[0], s[1], s[2], s[3]);
    }
}

__global__ __launch_bounds__(256) void k_pool(const float* __restrict__ x,
                                              const float* __restrict__ hattn,
                                              const float* __restrict__ wattn,
                                              float* __restrict__ ypool) {
    int plane = blockIdx.x;
    __shared__ float sm[PLANE];
    __shared__ float ha[56], wa[56];
    const float4* xp = (const float4*)(x + (size_t)plane * PLANE);
    float4* smp = (float4*)sm;
    int t = threadIdx.x;
    for (int f = t; f < PLANE / 4; f += 256) smp[f] = xp[f];
    if (t < 56) ha[t] = hattn[(size_t)plane * 56 + t];
    else if (t >= 64 && t < 120) wa[t - 64] = wattn[(size_t)plane * 56 + (t - 64)];
    __syncthreads();
    if (t < 64) {
        int i = t >> 3, j = t & 7;
        float s = 0.f;
#pragma unroll
        for (int dh = 0; dh < 7; ++dh) {
            float hv = ha[7 * i + dh];
            float r = 0.f;
#pragma unroll
            for (int dw = 0; dw < 7; ++dw)
                r += sm[(7 * i + dh) * 56 + 7 * j + dw] * wa[7 * j + dw];
            s += hv * r;
        }
        ypool[(size_t)plane * NPOOL + t] = s * (1.f / 49.f);
    }
}

__global__ __launch_bounds__(64) void k_attn(const float* __restrict__ ypool,
                                             const float* __restrict__ nsc,
                                             const float* __restrict__ nbi,
                                             const float* __restrict__ qw,
                                             const float* __restrict__ kw,
                                             const float* __restrict__ vw,
                                             float* __restrict__ ca) {
    int bh = blockIdx.x;
    int b = bh >> 3, h = bh & 7;
    int l = threadIdx.x;
    const float4* bp = (const float4*)(ypool + (size_t)b * NC * NPOOL);
    float s1 = 0.f, s2 = 0.f;
#pragma unroll
    for (int k = 0; k < 64; ++k) {
        float4 v = bp[l + 64 * k];
        s1 += v.x + v.y + v.z + v.w;
        s2 += v.x * v.x + v.y * v.y + v.z * v.z + v.w * v.w;
    }
#pragma unroll
    for (int off = 32; off >= 1; off >>= 1) {
        s1 += __shfl_xor(s1, off);
        s2 += __shfl_xor(s2, off);
    }
    float mean = s1 * (1.f / (NC * NPOOL));
    float var = s2 * (1.f / (NC * NPOOL)) - mean * mean;
    float rstd = rsqrtf(var + EPSV);

    __shared__ float yn[32][65];
    __shared__ float ybar[32];
    __shared__ float G[32][33];
    const float* base = ypool + ((size_t)b * NC + h * HDIM) * NPOOL;
#pragma unroll
    for (int m = 0; m < 32; ++m) {
        int idx = l + 64 * m;
        int d = idx >> 6, p = idx & 63;
        int ch = h * HDIM + d;
        float v = base[idx];
        yn[d][p] = (v - mean) * rstd * nsc[ch] + nbi[ch];
    }
    __syncthreads();
    if (l < 32) {
        float s = 0.f;
#pragma unroll
        for (int p = 0; p < 64; ++p) s += yn[l][p];
        ybar[l] = s * (1.f / 64.f);
    }
    __syncthreads();
#pragma unroll
    for (int m = 0; m < 16; ++m) {
        int idx = l + 64 * m;
        int d = idx >> 5, e = idx & 31;
        float s = 0.f;
#pragma unroll
        for (int p = 0; p < 64; ++p) s += yn[d][p] * yn[e][p];
        G[d][e] = s;
    }
    __syncthreads();
    if (l < 32) {
        int d = l, cd = h * HDIM + d;
        float qs = qw[cd] * 0.17677669529663687f;
        float a[32];
        float mx = -1e30f;
#pragma unroll
        for (int e = 0; e < 32; ++e) {
            a[e] = G[d][e] * qs * kw[h * HDIM + e];
            mx = fmaxf(mx, a[e]);
        }
        float sum = 0.f;
#pragma unroll
        for (int e = 0; e < 32; ++e) {
            a[e] = expf(a[e] - mx);
            sum += a[e];
        }
        float o = 0.f;
#pragma unroll
        for (int e = 0; e < 32; ++e) o += a[e] * vw[h * HDIM + e] * ybar[e];
        o /= sum;
        ca[b * NC + cd] = 1.f / (1.f + expf(-o));
    }
}

__global__ __launch_bounds__(256) void k_final(const float* __restrict__ x,
                                               const float* __restrict__ hattn,
                                               const float* __restrict__ wattn,
                                               const float* __restrict__ ca,
                                               float* __restrict__ out) {
    int plane = blockIdx.x;
    __shared__ float hv[56], wv[56];
    int t = threadIdx.x;
    float cav = ca[plane];
    if (t < 56) hv[t] = hattn[(size_t)plane * 56 + t] * cav;
    else if (t >= 64 && t < 120) wv[t - 64] = wattn[(size_t)plane * 56 + (t - 64)];
    __syncthreads();
    const float4* xp = (const float4*)(x + (size_t)plane * PLANE);
    float4* op = (float4*)(out + (size_t)plane * PLANE);
    for (int f = t; f < PLANE / 4; f += 256) {
        int r = f / 14;
        int s0 = (f - r * 14) * 4;
        float4 v = xp[f];
        float hf = hv[r];
        v.x *= hf * wv[s0];
        v.y *= hf * wv[s0 + 1];
        v.z *= hf * wv[s0 + 2];
        v.w *= hf * wv[s0 + 3];
        op[f] = v;
    }
}

extern "C" void kernel_launch(void* const* d_in, const int* in_sizes, int n_in,
                              void* d_out, int out_size, void* d_ws, size_t ws_size,
                              hipStream_t stream) {
    const float* x   = (const float*)d_in[0];
    const float* w3  = (const float*)d_in[1];
    const float* b3  = (const float*)d_in[2];
    const float* w5  = (const float*)d_in[3];
    const float* b5  = (const float*)d_in[4];
    const float* w7  = (const float*)d_in[5];
    const float* b7  = (const float*)d_in[6];
    const float* w9  = (const float*)d_in[7];
    const float* b9  = (const float*)d_in[8];
    const float* hsc = (const float*)d_in[9];
    const float* hbi = (const float*)d_in[10];
    const float* wsc = (const float*)d_in[11];
    const float* wbi = (const float*)d_in[12];
    const float* nsc = (const float*)d_in[13];
    const float* nbi = (const float*)d_in[14];
    const float* qw  = (const float*)d_in[15];
    const float* kw  = (const float*)d_in[16];
    const float* vw  = (const float*)d_in[17];
    float* out = (float*)d_out;

    float* ws    = (float*)d_ws;
    float* hm    = ws;
    float* wm    = hm + (size_t)NPLANE * 56;
    float* hattn = wm + (size_t)NPLANE * 56;
    float* wattn = hattn + (size_t)NPLANE * 56;
    float* ypool = wattn + (size_t)NPLANE * 56;
    float* ca    = ypool + (size_t)NPLANE * NPOOL;
    unsigned* bar = (unsigned*)(ca + (size_t)NB * NC);

    // Try cooperative mega-kernel; fall back to the proven 5-kernel path.
    bool coop_done = false;
    int maxb = 0;
    hipError_t qe = hipOccupancyMaxActiveBlocksPerMultiprocessor(
        &maxb, (const void*)k_mega, 256, 0);
    if (qe == hipSuccess && maxb * NUM_CU >= NBLK) {
        // Zero the pipeline counters (captured into the graph -> reset each replay).
        (void)hipMemsetAsync(bar, 0, 128 * sizeof(unsigned), stream);
        void* args[] = {
            (void*)&x,
            (void*)&w3, (void*)&b3, (void*)&w5, (void*)&b5,
            (void*)&w7, (void*)&b7, (void*)&w9, (void*)&b9,
            (void*)&hsc, (void*)&hbi, (void*)&wsc, (void*)&wbi,
            (void*)&nsc, (void*)&nbi,
            (void*)&qw, (void*)&kw, (void*)&vw,
            (void*)&hm, (void*)&wm, (void*)&hattn, (void*)&wattn,
            (void*)&ypool, (void*)&ca, (void*)&out, (void*)&bar
        };
        hipError_t le = hipLaunchCooperativeKernel((const void*)k_mega, dim3(NBLK),
                                                   dim3(256), args, 0, stream);
        coop_done = (le == hipSuccess);
    }
    if (!coop_done) {
        (void)hipGetLastError();  // clear any sticky error from the rejected launch
        k_means<<<NPLANE, 256, 0, stream>>>(x, hm, wm);
        k_branch<<<2 * NB, 256, 0, stream>>>(hm, wm, w3, b3, w5, b5, w7, b7, w9, b9,
                                             hsc, hbi, wsc, wbi, hattn, wattn);
        k_pool<<<NPLANE, 256, 0, stream>>>(x, hattn, wattn, ypool);
        k_attn<<<NB * NHEADS, 64, 0, stream>>>(ypool, nsc, nbi, qw, kw, vw, ca);
        k_final<<<NPLANE, 256, 0, stream>>>(x, hattn, wattn, ca, out);
    }
}

// Round 4
// 356.901 us; speedup vs baseline: 1.3153x; 1.1222x over previous
//
#include <hip/hip_runtime.h>
#include <cstdint>
#include <cstddef>

#define NB 32        // batch
#define NC 256       // channels
#define HW 56        // spatial
#define PLANE (HW*HW)       // 3136
#define NPLANE (NB*NC)      // 8192
#define NHEADS 8
#define HDIM 32
#define NPOOL 64            // 8*8
#define EPSV 1e-5f
#define NBLK 1024
#define PPB (NPLANE/NBLK)   // 8 planes per block in streaming phases
#define NUM_CU 256

// LDS union kept <= 14.6 KB so 4 blocks/CU fit even under a 64 KB/CU calc.
struct Ph13 { float buf[PLANE]; float ha[56]; float wa[56]; };   // 12992 B
struct Ph2  { float rows[64*57]; float red[8]; };                // 14624 B (max)
struct Ph4  { float yn[32][65]; float G[32][33]; float ybar[32]; float red[8]; float stats[2]; };
struct Ph5  { float hv[8][56]; float wv[8][56]; };               // 3584 B
union SmemU { Ph13 a; Ph2 b; Ph4 c; Ph5 d; };

// ---- LLC-coherent (cross-XCD) scalar access for intermediates.
// Relaxed agent-scope atomics compile to sc0 sc1 loads/stores: they bypass the
// non-coherent per-XCD L2 and are served by the memory-side Infinity Cache.
__device__ __forceinline__ float cload(const float* p) {
    return __hip_atomic_load(p, __ATOMIC_RELAXED, __HIP_MEMORY_SCOPE_AGENT);
}
__device__ __forceinline__ void cstore(float* p, float v) {
    __hip_atomic_store(p, v, __ATOMIC_RELAXED, __HIP_MEMORY_SCOPE_AGENT);
}

// ---- per-batch pipeline flags (no grid-wide barrier).
// arrive: __syncthreads drains each wave's sc1 stores (vmcnt) before the
// leader's LLC fetch_add, so counter==target implies producer data visible.
__device__ __forceinline__ void arrive_flag(unsigned* c) {
    __syncthreads();
    if (threadIdx.x == 0)
        __hip_atomic_fetch_add(c, 1u, __ATOMIC_RELAXED, __HIP_MEMORY_SCOPE_AGENT);
}
__device__ __forceinline__ void wait_flag(const unsigned* c, unsigned tgt) {
    if (threadIdx.x == 0) {
        while (__hip_atomic_load(c, __ATOMIC_RELAXED, __HIP_MEMORY_SCOPE_AGENT) < tgt) {
            __builtin_amdgcn_s_sleep(2);
        }
        asm volatile("" ::: "memory");   // compiler-only fence; HW coherence via sc1
    }
    __syncthreads();
}

// ---- phase 2 worker: depthwise conv (uniform K per block) + GroupNorm(group==block) + sigmoid
template<int K>
__device__ __forceinline__ void ph2_work(const float* __restrict__ src,
                                         const float* __restrict__ wk,
                                         const float* __restrict__ bk,
                                         const float* __restrict__ scale,
                                         const float* __restrict__ bias,
                                         float* __restrict__ dst,
                                         int cbase, Ph2* S2, int t) {
#pragma unroll
    for (int k2 = 0; k2 < 4; ++k2) {
        int f = t + 256 * k2;
        if (f < 896) {
            int c = f / 14, r = f - c * 14;
            float* d = &S2->rows[c * 57 + r * 4];
            const float* s = src + f * 4;
            d[0] = cload(s); d[1] = cload(s + 1); d[2] = cload(s + 2); d[3] = cload(s + 3);
        }
    }
    __syncthreads();
    int cc = t >> 2, q = t & 3;          // channel-in-group, quarter
    float w[K];
#pragma unroll
    for (int j = 0; j < K; ++j) w[j] = wk[cc * K + j];
    float bb = bk[cc];
    const float* row = &S2->rows[cc * 57];
    float y[14];
    float s1 = 0.f, s2 = 0.f;
#pragma unroll
    for (int il = 0; il < 14; ++il) {
        int pos = q * 14 + il;
        float a = bb;
#pragma unroll
        for (int j = 0; j < K; ++j) {
            int p2 = pos + j - K / 2;
            if (p2 >= 0 && p2 < 56) a += w[j] * row[p2];
        }
        y[il] = a; s1 += a; s2 += a * a;
    }
#pragma unroll
    for (int off = 32; off >= 1; off >>= 1) {
        s1 += __shfl_xor(s1, off);
        s2 += __shfl_xor(s2, off);
    }
    int wv = t >> 6;
    if ((t & 63) == 0) { S2->red[wv] = s1; S2->red[4 + wv] = s2; }
    __syncthreads();
    float t1 = S2->red[0] + S2->red[1] + S2->red[2] + S2->red[3];
    float t2 = S2->red[4] + S2->red[5] + S2->red[6] + S2->red[7];
    float mean = t1 * (1.f / 3584.f);
    float var = t2 * (1.f / 3584.f) - mean * mean;
    float rstd = rsqrtf(var + EPSV);
    int c = cbase + cc;
    float scv = scale[c];
    float a_lin = scv * rstd, b_lin = bias[c] - mean * rstd * scv;
#pragma unroll
    for (int il = 0; il < 14; ++il) {
        float v = y[il] * a_lin + b_lin;
        S2->rows[cc * 57 + q * 14 + il] = 1.f / (1.f + expf(-v));
    }
    __syncthreads();
#pragma unroll
    for (int k2 = 0; k2 < 4; ++k2) {
        int f = t + 256 * k2;
        if (f < 896) {
            int c2 = f / 14, r = f - c2 * 14;
            const float* s = &S2->rows[c2 * 57 + r * 4];
            float* d = dst + f * 4;
            cstore(d, s[0]); cstore(d + 1, s[1]); cstore(d + 2, s[2]); cstore(d + 3, s[3]);
        }
    }
}

// Per-batch pipelined mega-kernel. Block bid serves batch b = bid>>5 through
// all phases (rank r = bid&31). Stage completion tracked by per-batch LLC
// counters: c1[b]=32 (means), c2[b]=8 (gates), c3[b]=32 (pool), c4[b]=8 (ca).
// No grid-wide sync and NO cooperative-launch dependency: co-residency is
// guaranteed by capacity arithmetic (__launch_bounds__(256,4) -> 4 blk/CU x
// 256 CU = 1024 = grid), so a plain (graph-capturable) launch is safe.
__global__ __launch_bounds__(256, 4) void k_mega(
    const float* __restrict__ x,
    const float* __restrict__ w3, const float* __restrict__ b3,
    const float* __restrict__ w5, const float* __restrict__ b5,
    const float* __restrict__ w7, const float* __restrict__ b7,
    const float* __restrict__ w9, const float* __restrict__ b9,
    const float* __restrict__ hsc, const float* __restrict__ hbi,
    const float* __restrict__ wsc, const float* __restrict__ wbi,
    const float* __restrict__ nsc, const float* __restrict__ nbi,
    const float* __restrict__ qw, const float* __restrict__ kw,
    const float* __restrict__ vw,
    float* __restrict__ hm, float* __restrict__ wm,
    float* __restrict__ hattn, float* __restrict__ wattn,
    float* __restrict__ ypool, float* __restrict__ ca,
    float* __restrict__ out, unsigned* __restrict__ bar)
{
    __shared__ SmemU S;
    const int t = threadIdx.x;
    const int bid = blockIdx.x;
    const int b = bid >> 5;      // batch this block serves for its whole life
    const int r = bid & 31;      // rank within the batch's 32 blocks
    unsigned* c1 = bar;          // P1 done   (target 32)
    unsigned* c2 = bar + 32;     // P2 done   (target 8)
    unsigned* c3 = bar + 64;     // P3 done   (target 32)
    unsigned* c4 = bar + 96;     // P4 done   (target 8)

    // ============ Phase 1: per-plane row/col means (8 planes: bid*8+p) ============
    for (int p = 0; p < PPB; ++p) {
        int plane = bid * PPB + p;
        {
            const float4* xp = (const float4*)(x + (size_t)plane * PLANE);
            float4* smp = (float4*)S.a.buf;
            for (int f = t; f < PLANE / 4; f += 256) smp[f] = xp[f];
        }
        __syncthreads();
        const float* sm = S.a.buf;
        if (t < 224) {
            int a = t >> 2, q = t & 3;
            float s = 0.f;
#pragma unroll
            for (int i = 0; i < 14; ++i) s += sm[a * 56 + q * 14 + i];
            s += __shfl_xor(s, 1); s += __shfl_xor(s, 2);
            if (q == 0) cstore(&hm[(size_t)plane * 56 + a], s * (1.f / 56.f));
            float s2 = 0.f;
#pragma unroll
            for (int i = 0; i < 14; ++i) s2 += sm[(q * 14 + i) * 56 + a];
            s2 += __shfl_xor(s2, 1); s2 += __shfl_xor(s2, 2);
            if (q == 0) cstore(&wm[(size_t)plane * 56 + a], s2 * (1.f / 56.f));
        }
        __syncthreads();
    }
    arrive_flag(c1 + b);

    // ============ Phase 2: sa_branch (conv + GN4 + sigmoid), 8 jobs/batch ============
    if (r < 8) {
        wait_flag(c1 + b, 32);
        int mode = r & 1, g = r >> 1;
        const float* src = (mode ? wm : hm) + ((size_t)b * NC + g * 64) * 56;
        float* dst = (mode ? wattn : hattn) + ((size_t)b * NC + g * 64) * 56;
        const float* scale = mode ? wsc : hsc;
        const float* bias = mode ? wbi : hbi;
        switch (g) {
            case 0: ph2_work<3>(src, w3, b3, scale, bias, dst, 0,   &S.b, t); break;
            case 1: ph2_work<5>(src, w5, b5, scale, bias, dst, 64,  &S.b, t); break;
            case 2: ph2_work<7>(src, w7, b7, scale, bias, dst, 128, &S.b, t); break;
            default: ph2_work<9>(src, w9, b9, scale, bias, dst, 192, &S.b, t); break;
        }
        arrive_flag(c2 + b);
    }

    // ============ Phase 3: gated 7x7 avgpool -> ypool ============
    wait_flag(c2 + b, 8);
    for (int p = 0; p < PPB; ++p) {
        int plane = bid * PPB + p;
        {
            const float4* xp = (const float4*)(x + (size_t)plane * PLANE);
            float4* smp = (float4*)S.a.buf;
            for (int f = t; f < PLANE / 4; f += 256) smp[f] = xp[f];
            if (t < 56) S.a.ha[t] = cload(&hattn[(size_t)plane * 56 + t]);
            else if (t >= 64 && t < 120) S.a.wa[t - 64] = cload(&wattn[(size_t)plane * 56 + (t - 64)]);
        }
        __syncthreads();
        {
            const float* sm = S.a.buf;
            const float* ha = S.a.ha;
            const float* wa = S.a.wa;
            int cell = t >> 2, sub = t & 3;
            int i = cell >> 3, j = cell & 7;
            float s = 0.f;
#pragma unroll
            for (int k2 = 0; k2 < 2; ++k2) {
                int dh = sub + 4 * k2;
                if (dh < 7) {
                    float rr = 0.f;
#pragma unroll
                    for (int dw = 0; dw < 7; ++dw)
                        rr += sm[(7 * i + dh) * 56 + 7 * j + dw] * wa[7 * j + dw];
                    s += ha[7 * i + dh] * rr;
                }
            }
            s += __shfl_xor(s, 1); s += __shfl_xor(s, 2);
            if (sub == 0) cstore(&ypool[(size_t)plane * NPOOL + cell], s * (1.f / 49.f));
        }
        __syncthreads();
    }
    arrive_flag(c3 + b);

    // ============ Phase 4: GN1 stats + attention -> ca, 8 jobs/batch ============
    if (r < 8) {
        wait_flag(c3 + b, 32);
        int h = r;
        const float* bp = ypool + (size_t)b * NC * NPOOL;
        float s1 = 0.f, s2 = 0.f;
#pragma unroll
        for (int k2 = 0; k2 < 16; ++k2) {
            int i4 = (t + 256 * k2) * 4;
            float vx = cload(bp + i4), vy = cload(bp + i4 + 1);
            float vz = cload(bp + i4 + 2), vw2 = cload(bp + i4 + 3);
            s1 += vx + vy + vz + vw2;
            s2 += vx * vx + vy * vy + vz * vz + vw2 * vw2;
        }
#pragma unroll
        for (int off = 32; off >= 1; off >>= 1) {
            s1 += __shfl_xor(s1, off);
            s2 += __shfl_xor(s2, off);
        }
        if ((t & 63) == 0) { S.c.red[t >> 6] = s1; S.c.red[4 + (t >> 6)] = s2; }
        __syncthreads();
        if (t == 0) {
            float t1 = S.c.red[0] + S.c.red[1] + S.c.red[2] + S.c.red[3];
            float t2 = S.c.red[4] + S.c.red[5] + S.c.red[6] + S.c.red[7];
            float mean = t1 * (1.f / (NC * NPOOL));
            float var = t2 * (1.f / (NC * NPOOL)) - mean * mean;
            S.c.stats[0] = mean; S.c.stats[1] = rsqrtf(var + EPSV);
        }
        __syncthreads();
        float mean = S.c.stats[0], rstd = S.c.stats[1];
        const float* base = ypool + ((size_t)b * NC + h * HDIM) * NPOOL;
#pragma unroll
        for (int m = 0; m < 8; ++m) {
            int idx = t + 256 * m;
            int d = idx >> 6, p = idx & 63;
            int ch = h * HDIM + d;
            S.c.yn[d][p] = (cload(&base[idx]) - mean) * rstd * nsc[ch] + nbi[ch];
        }
        __syncthreads();
        if (t < 32) {
            float s = 0.f;
#pragma unroll
            for (int p = 0; p < 64; ++p) s += S.c.yn[t][p];
            S.c.ybar[t] = s * (1.f / 64.f);
        }
        __syncthreads();
#pragma unroll
        for (int m = 0; m < 4; ++m) {
            int idx = t + 256 * m;
            int d = idx >> 5, e = idx & 31;
            float s = 0.f;
#pragma unroll
            for (int p = 0; p < 64; ++p) s += S.c.yn[d][p] * S.c.yn[e][p];
            S.c.G[d][e] = s;
        }
        __syncthreads();
        if (t < 32) {
            int d = t, cd = h * HDIM + d;
            float qs = qw[cd] * 0.17677669529663687f;  // 1/sqrt(32)
            float a[32];
            float mx = -1e30f;
#pragma unroll
            for (int e = 0; e < 32; ++e) {
                a[e] = S.c.G[d][e] * qs * kw[h * HDIM + e];
                mx = fmaxf(mx, a[e]);
            }
            float sum = 0.f;
#pragma unroll
            for (int e = 0; e < 32; ++e) {
                a[e] = expf(a[e] - mx);
                sum += a[e];
            }
            float o = 0.f;
#pragma unroll
            for (int e = 0; e < 32; ++e) o += a[e] * vw[h * HDIM + e] * S.c.ybar[e];
            o /= sum;
            cstore(&ca[b * NC + cd], 1.f / (1.f + expf(-o)));
        }
        arrive_flag(c4 + b);
    }

    // ============ Phase 5: out = x * hattn * wattn * ca ============
    wait_flag(c4 + b, 8);
    {
        for (int i = t; i < 448; i += 256) {
            int p = i / 56, a = i - p * 56;
            int pl = bid * PPB + p;
            S.d.hv[p][a] = cload(&hattn[(size_t)pl * 56 + a]) * cload(&ca[pl]);
            S.d.wv[p][a] = cload(&wattn[(size_t)pl * 56 + a]);
        }
        __syncthreads();
        for (int p = 0; p < PPB; ++p) {
            int plane = bid * PPB + p;
            const float* hv = S.d.hv[p];
            const float* wv = S.d.wv[p];
            const float4* xp = (const float4*)(x + (size_t)plane * PLANE);
            float4* op = (float4*)(out + (size_t)plane * PLANE);
            for (int f = t; f < PLANE / 4; f += 256) {
                int rr = f / 14, s0 = (f - rr * 14) * 4;
                float4 v = xp[f];
                float hf = hv[rr];
                v.x *= hf * wv[s0];
                v.y *= hf * wv[s0 + 1];
                v.z *= hf * wv[s0 + 2];
                v.w *= hf * wv[s0 + 3];
                op[f] = v;
            }
        }
    }
}

// ======================= Fallback path (known-good) =======================
__global__ __launch_bounds__(256) void k_means(const float* __restrict__ x,
                                               float* __restrict__ hm,
                                               float* __restrict__ wm) {
    int plane = blockIdx.x;
    __shared__ float sm[PLANE];
    const float4* xp = (const float4*)(x + (size_t)plane * PLANE);
    float4* smp = (float4*)sm;
    int t = threadIdx.x;
    for (int f = t; f < PLANE / 4; f += 256) smp[f] = xp[f];
    __syncthreads();
    if (t < 224) {
        int a = t >> 2, q = t & 3;
        float s = 0.f;
#pragma unroll
        for (int i = 0; i < 14; ++i) s += sm[a * 56 + q * 14 + i];
        s += __shfl_xor(s, 1); s += __shfl_xor(s, 2);
        if (q == 0) hm[(size_t)plane * 56 + a] = s * (1.f / 56.f);
        float s2 = 0.f;
#pragma unroll
        for (int i = 0; i < 14; ++i) s2 += sm[(q * 14 + i) * 56 + a];
        s2 += __shfl_xor(s2, 1); s2 += __shfl_xor(s2, 2);
        if (q == 0) wm[(size_t)plane * 56 + a] = s2 * (1.f / 56.f);
    }
}

__global__ __launch_bounds__(256) void k_branch(
    const float* __restrict__ hm, const float* __restrict__ wm,
    const float* __restrict__ w3, const float* __restrict__ b3,
    const float* __restrict__ w5, const float* __restrict__ b5,
    const float* __restrict__ w7, const float* __restrict__ b7,
    const float* __restrict__ w9, const float* __restrict__ b9,
    const float* __restrict__ hsc, const float* __restrict__ hbi,
    const float* __restrict__ wsc, const float* __restrict__ wbi,
    float* __restrict__ hattn, float* __restrict__ wattn) {
    int mode = blockIdx.x & 1;
    int b = blockIdx.x >> 1;
    const float* src = (mode == 0 ? hm : wm) + (size_t)b * NC * 56;
    const float* scale = (mode == 0 ? hsc : wsc);
    const float* bias = (mode == 0 ? hbi : wbi);
    float* dst = (mode == 0 ? hattn : wattn) + (size_t)b * NC * 56;

    __shared__ float sm[NC * 57];
    int t = threadIdx.x;
    const float4* sp = (const float4*)src;
#pragma unroll
    for (int k = 0; k < 14; ++k) {
        int f = t + 256 * k;
        float4 v = sp[f];
        int c = f / 14, r = f - c * 14;
        float* d = &sm[c * 57 + r * 4];
        d[0] = v.x; d[1] = v.y; d[2] = v.z; d[3] = v.w;
    }
    __syncthreads();

    int c = t;
    int g = c >> 6, cc = c & 63;
    float wc[9];
#pragma unroll
    for (int i = 0; i < 9; ++i) wc[i] = 0.f;
    float bb = 0.f;
    if (g == 0) {
#pragma unroll
        for (int q = 0; q < 3; ++q) wc[3 + q] = w3[cc * 3 + q];
        bb = b3[cc];
    } else if (g == 1) {
#pragma unroll
        for (int q = 0; q < 5; ++q) wc[2 + q] = w5[cc * 5 + q];
        bb = b5[cc];
    } else if (g == 2) {
#pragma unroll
        for (int q = 0; q < 7; ++q) wc[1 + q] = w7[cc * 7 + q];
        bb = b7[cc];
    } else {
#pragma unroll
        for (int q = 0; q < 9; ++q) wc[q] = w9[cc * 9 + q];
        bb = b9[cc];
    }

    float xv[56];
#pragma unroll
    for (int i = 0; i < 56; ++i) xv[i] = sm[c * 57 + i];

    float s1 = 0.f, s2 = 0.f;
#pragma unroll
    for (int i = 0; i < 56; ++i) {
        float a = bb;
#pragma unroll
        for (int d = 0; d < 9; ++d) {
            int j = i + d - 4;
            if (j >= 0 && j < 56) a += wc[d] * xv[j];
        }
        s1 += a;
        s2 += a * a;
    }
#pragma unroll
    for (int off = 32; off >= 1; off >>= 1) {
        s1 += __shfl_xor(s1, off);
        s2 += __shfl_xor(s2, off);
    }
    float mean = s1 * (1.f / 3584.f);
    float var = s2 * (1.f / 3584.f) - mean * mean;
    float rstd = rsqrtf(var + EPSV);
    float scv = scale[c];
    float a_lin = scv * rstd;
    float b_lin = bias[c] - mean * rstd * scv;
#pragma unroll
    for (int i = 0; i < 56; ++i) {
        float a = bb;
#pragma unroll
        for (int d = 0; d < 9; ++d) {
            int j = i + d - 4;
            if (j >= 0 && j < 56) a += wc[d] * xv[j];
        }
        float v = a * a_lin + b_lin;
        sm[c * 57 + i] = 1.f / (1.f + expf(-v));
    }
    __syncthreads();
    float4* dp = (float4*)dst;
#pragma unroll
    for (int k = 0; k < 14; ++k) {
        int f = t + 256 * k;
        int c2 = f / 14, r = f - c2 * 14;
        const float* s = &sm[c2 * 57 + r * 4];
        dp[f] = make_float4(s[0], s[1], s[2], s[3]);
    }
}

__global__ __launch_bounds__(256) void k_pool(const float* __restrict__ x,
                                              const float* __restrict__ hattn,
                                              const float* __restrict__ wattn,
                                              float* __restrict__ ypool) {
    int plane = blockIdx.x;
    __shared__ float sm[PLANE];
    __shared__ float ha[56], wa[56];
    const float4* xp = (const float4*)(x + (size_t)plane * PLANE);
    float4* smp = (float4*)sm;
    int t = threadIdx.x;
    for (int f = t; f < PLANE / 4; f += 256) smp[f] = xp[f];
    if (t < 56) ha[t] = hattn[(size_t)plane * 56 + t];
    else if (t >= 64 && t < 120) wa[t - 64] = wattn[(size_t)plane * 56 + (t - 64)];
    __syncthreads();
    if (t < 64) {
        int i = t >> 3, j = t & 7;
        float s = 0.f;
#pragma unroll
        for (int dh = 0; dh < 7; ++dh) {
            float hv = ha[7 * i + dh];
            float r = 0.f;
#pragma unroll
            for (int dw = 0; dw < 7; ++dw)
                r += sm[(7 * i + dh) * 56 + 7 * j + dw] * wa[7 * j + dw];
            s += hv * r;
        }
        ypool[(size_t)plane * NPOOL + t] = s * (1.f / 49.f);
    }
}

__global__ __launch_bounds__(64) void k_attn(const float* __restrict__ ypool,
                                             const float* __restrict__ nsc,
                                             const float* __restrict__ nbi,
                                             const float* __restrict__ qw,
                                             const float* __restrict__ kw,
                                             const float* __restrict__ vw,
                                             float* __restrict__ ca) {
    int bh = blockIdx.x;
    int b = bh >> 3, h = bh & 7;
    int l = threadIdx.x;
    const float4* bp = (const float4*)(ypool + (size_t)b * NC * NPOOL);
    float s1 = 0.f, s2 = 0.f;
#pragma unroll
    for (int k = 0; k < 64; ++k) {
        float4 v = bp[l + 64 * k];
        s1 += v.x + v.y + v.z + v.w;
        s2 += v.x * v.x + v.y * v.y + v.z * v.z + v.w * v.w;
    }
#pragma unroll
    for (int off = 32; off >= 1; off >>= 1) {
        s1 += __shfl_xor(s1, off);
        s2 += __shfl_xor(s2, off);
    }
    float mean = s1 * (1.f / (NC * NPOOL));
    float var = s2 * (1.f / (NC * NPOOL)) - mean * mean;
    float rstd = rsqrtf(var + EPSV);

    __shared__ float yn[32][65];
    __shared__ float ybar[32];
    __shared__ float G[32][33];
    const float* base = ypool + ((size_t)b * NC + h * HDIM) * NPOOL;
#pragma unroll
    for (int m = 0; m < 32; ++m) {
        int idx = l + 64 * m;
        int d = idx >> 6, p = idx & 63;
        int ch = h * HDIM + d;
        float v = base[idx];
        yn[d][p] = (v - mean) * rstd * nsc[ch] + nbi[ch];
    }
    __syncthreads();
    if (l < 32) {
        float s = 0.f;
#pragma unroll
        for (int p = 0; p < 64; ++p) s += yn[l][p];
        ybar[l] = s * (1.f / 64.f);
    }
    __syncthreads();
#pragma unroll
    for (int m = 0; m < 16; ++m) {
        int idx = l + 64 * m;
        int d = idx >> 5, e = idx & 31;
        float s = 0.f;
#pragma unroll
        for (int p = 0; p < 64; ++p) s += yn[d][p] * yn[e][p];
        G[d][e] = s;
    }
    __syncthreads();
    if (l < 32) {
        int d = l, cd = h * HDIM + d;
        float qs = qw[cd] * 0.17677669529663687f;
        float a[32];
        float mx = -1e30f;
#pragma unroll
        for (int e = 0; e < 32; ++e) {
            a[e] = G[d][e] * qs * kw[h * HDIM + e];
            mx = fmaxf(mx, a[e]);
        }
        float sum = 0.f;
#pragma unroll
        for (int e = 0; e < 32; ++e) {
            a[e] = expf(a[e] - mx);
            sum += a[e];
        }
        float o = 0.f;
#pragma unroll
        for (int e = 0; e < 32; ++e) o += a[e] * vw[h * HDIM + e] * ybar[e];
        o /= sum;
        ca[b * NC + cd] = 1.f / (1.f + expf(-o));
    }
}

__global__ __launch_bounds__(256) void k_final(const float* __restrict__ x,
                                               const float* __restrict__ hattn,
                                               const float* __restrict__ wattn,
                                               const float* __restrict__ ca,
                                               float* __restrict__ out) {
    int plane = blockIdx.x;
    __shared__ float hv[56], wv[56];
    int t = threadIdx.x;
    float cav = ca[plane];
    if (t < 56) hv[t] = hattn[(size_t)plane * 56 + t] * cav;
    else if (t >= 64 && t < 120) wv[t - 64] = wattn[(size_t)plane * 56 + (t - 64)];
    __syncthreads();
    const float4* xp = (const float4*)(x + (size_t)plane * PLANE);
    float4* op = (float4*)(out + (size_t)plane * PLANE);
    for (int f = t; f < PLANE / 4; f += 256) {
        int r = f / 14;
        int s0 = (f - r * 14) * 4;
        float4 v = xp[f];
        float hf = hv[r];
        v.x *= hf * wv[s0];
        v.y *= hf * wv[s0 + 1];
        v.z *= hf * wv[s0 + 2];
        v.w *= hf * wv[s0 + 3];
        op[f] = v;
    }
}

extern "C" void kernel_launch(void* const* d_in, const int* in_sizes, int n_in,
                              void* d_out, int out_size, void* d_ws, size_t ws_size,
                              hipStream_t stream) {
    const float* x   = (const float*)d_in[0];
    const float* w3  = (const float*)d_in[1];
    const float* b3  = (const float*)d_in[2];
    const float* w5  = (const float*)d_in[3];
    const float* b5  = (const float*)d_in[4];
    const float* w7  = (const float*)d_in[5];
    const float* b7  = (const float*)d_in[6];
    const float* w9  = (const float*)d_in[7];
    const float* b9  = (const float*)d_in[8];
    const float* hsc = (const float*)d_in[9];
    const float* hbi = (const float*)d_in[10];
    const float* wsc = (const float*)d_in[11];
    const float* wbi = (const float*)d_in[12];
    const float* nsc = (const float*)d_in[13];
    const float* nbi = (const float*)d_in[14];
    const float* qw  = (const float*)d_in[15];
    const float* kw  = (const float*)d_in[16];
    const float* vw  = (const float*)d_in[17];
    float* out = (float*)d_out;

    float* ws    = (float*)d_ws;
    float* hm    = ws;
    float* wm    = hm + (size_t)NPLANE * 56;
    float* hattn = wm + (size_t)NPLANE * 56;
    float* wattn = hattn + (size_t)NPLANE * 56;
    float* ypool = wattn + (size_t)NPLANE * 56;
    float* ca    = ypool + (size_t)NPLANE * NPOOL;
    unsigned* bar = (unsigned*)(ca + (size_t)NB * NC);

    // Residency guard: the flag pipeline needs all NBLK blocks co-resident.
    // __launch_bounds__(256,4) gives 4 blk/CU x 256 CU = 1024 = NBLK, verified
    // at runtime. Plain launch (graph-capturable) -- the timed path and the
    // profiled path now execute the same kernel.
    bool mega_ok = false;
    int maxb = 0;
    hipError_t qe = hipOccupancyMaxActiveBlocksPerMultiprocessor(
        &maxb, (const void*)k_mega, 256, 0);
    if (qe == hipSuccess && maxb * NUM_CU >= NBLK) {
        // Zero the pipeline counters (captured into the graph -> reset each replay).
        (void)hipMemsetAsync(bar, 0, 128 * sizeof(unsigned), stream);
        k_mega<<<dim3(NBLK), dim3(256), 0, stream>>>(
            x, w3, b3, w5, b5, w7, b7, w9, b9,
            hsc, hbi, wsc, wbi, nsc, nbi, qw, kw, vw,
            hm, wm, hattn, wattn, ypool, ca, out, bar);
        mega_ok = (hipGetLastError() == hipSuccess);
    }
    if (!mega_ok) {
        (void)hipGetLastError();  // clear any sticky error
        k_means<<<NPLANE, 256, 0, stream>>>(x, hm, wm);
        k_branch<<<2 * NB, 256, 0, stream>>>(hm, wm, w3, b3, w5, b5, w7, b7, w9, b9,
                                             hsc, hbi, wsc, wbi, hattn, wattn);
        k_pool<<<NPLANE, 256, 0, stream>>>(x, hattn, wattn, ypool);
        k_attn<<<NB * NHEADS, 64, 0, stream>>>(ypool, nsc, nbi, qw, kw, vw, ca);
        k_final<<<NPLANE, 256, 0, stream>>>(x, hattn, wattn, ca, out);
    }
}

// Round 6
// 260.332 us; speedup vs baseline: 1.8032x; 1.3709x over previous
//
#include <hip/hip_runtime.h>
#include <cstdint>
#include <cstddef>

#define NB 32        // batch
#define NC 256       // channels
#define HW 56        // spatial
#define PLANE (HW*HW)       // 3136
#define NPLANE (NB*NC)      // 8192
#define NHEADS 8
#define HDIM 32
#define NPOOL 64            // 8*8
#define EPSV 1e-5f

struct Ph2 { float rows[64*57]; float red[8]; };   // 14624 B

// ---- phase 2 worker: depthwise conv (uniform K per block) + GroupNorm(group==block) + sigmoid
// 256 blocks: bid -> mode=bid&1 (h/w), b=(bid>>1)&31, g=bid>>6 (kernel-size group).
template<int K>
__device__ __forceinline__ void ph2_work(const float* __restrict__ src,
                                         const float* __restrict__ wk,
                                         const float* __restrict__ bk,
                                         const float* __restrict__ scale,
                                         const float* __restrict__ bias,
                                         float* __restrict__ dst,
                                         int cbase, Ph2* S2, int t) {
    const float4* sp = (const float4*)src;
#pragma unroll
    for (int k2 = 0; k2 < 4; ++k2) {
        int f = t + 256 * k2;
        if (f < 896) {
            float4 v = sp[f];
            int c = f / 14, r = f - c * 14;
            float* d = &S2->rows[c * 57 + r * 4];
            d[0] = v.x; d[1] = v.y; d[2] = v.z; d[3] = v.w;
        }
    }
    __syncthreads();
    int cc = t >> 2, q = t & 3;          // channel-in-group, quarter of the 56 positions
    float w[K];
#pragma unroll
    for (int j = 0; j < K; ++j) w[j] = wk[cc * K + j];
    float bb = bk[cc];
    const float* row = &S2->rows[cc * 57];
    float y[14];
    float s1 = 0.f, s2 = 0.f;
#pragma unroll
    for (int il = 0; il < 14; ++il) {
        int pos = q * 14 + il;
        float a = bb;
#pragma unroll
        for (int j = 0; j < K; ++j) {
            int p2 = pos + j - K / 2;
            if (p2 >= 0 && p2 < 56) a += w[j] * row[p2];
        }
        y[il] = a; s1 += a; s2 += a * a;
    }
#pragma unroll
    for (int off = 32; off >= 1; off >>= 1) {
        s1 += __shfl_xor(s1, off);
        s2 += __shfl_xor(s2, off);
    }
    int wv = t >> 6;
    if ((t & 63) == 0) { S2->red[wv] = s1; S2->red[4 + wv] = s2; }
    __syncthreads();
    float t1 = S2->red[0] + S2->red[1] + S2->red[2] + S2->red[3];
    float t2 = S2->red[4] + S2->red[5] + S2->red[6] + S2->red[7];
    float mean = t1 * (1.f / 3584.f);
    float var = t2 * (1.f / 3584.f) - mean * mean;
    float rstd = rsqrtf(var + EPSV);
    int c = cbase + cc;
    float scv = scale[c];
    float a_lin = scv * rstd, b_lin = bias[c] - mean * rstd * scv;
#pragma unroll
    for (int il = 0; il < 14; ++il) {
        float v = y[il] * a_lin + b_lin;
        S2->rows[cc * 57 + q * 14 + il] = 1.f / (1.f + expf(-v));
    }
    __syncthreads();
    float4* dp = (float4*)dst;
#pragma unroll
    for (int k2 = 0; k2 < 4; ++k2) {
        int f = t + 256 * k2;
        if (f < 896) {
            int c2 = f / 14, r = f - c2 * 14;
            const float* s = &S2->rows[c2 * 57 + r * 4];
            dp[f] = make_float4(s[0], s[1], s[2], s[3]);
        }
    }
}

// ============ K1: per-plane row/col means ============
__global__ __launch_bounds__(256) void k_means(const float* __restrict__ x,
                                               float* __restrict__ hm,
                                               float* __restrict__ wm) {
    int plane = blockIdx.x;
    __shared__ float sm[PLANE];
    const float4* xp = (const float4*)(x + (size_t)plane * PLANE);
    float4* smp = (float4*)sm;
    int t = threadIdx.x;
    for (int f = t; f < PLANE / 4; f += 256) smp[f] = xp[f];
    __syncthreads();
    if (t < 224) {
        int a = t >> 2, q = t & 3;
        float s = 0.f;
#pragma unroll
        for (int i = 0; i < 14; ++i) s += sm[a * 56 + q * 14 + i];
        s += __shfl_xor(s, 1); s += __shfl_xor(s, 2);
        if (q == 0) hm[(size_t)plane * 56 + a] = s * (1.f / 56.f);
        float s2 = 0.f;
#pragma unroll
        for (int i = 0; i < 14; ++i) s2 += sm[(q * 14 + i) * 56 + a];
        s2 += __shfl_xor(s2, 1); s2 += __shfl_xor(s2, 2);
        if (q == 0) wm[(size_t)plane * 56 + a] = s2 * (1.f / 56.f);
    }
}

// ============ K2: sa_branch (conv + GN4 + sigmoid), 256 blocks ============
__global__ __launch_bounds__(256) void k_branch(
    const float* __restrict__ hm, const float* __restrict__ wm,
    const float* __restrict__ w3, const float* __restrict__ b3,
    const float* __restrict__ w5, const float* __restrict__ b5,
    const float* __restrict__ w7, const float* __restrict__ b7,
    const float* __restrict__ w9, const float* __restrict__ b9,
    const float* __restrict__ hsc, const float* __restrict__ hbi,
    const float* __restrict__ wsc, const float* __restrict__ wbi,
    float* __restrict__ hattn, float* __restrict__ wattn) {
    __shared__ Ph2 S2;
    int t = threadIdx.x, bid = blockIdx.x;
    int mode = bid & 1, b = (bid >> 1) & 31, g = bid >> 6;
    const float* src = (mode ? wm : hm) + ((size_t)b * NC + g * 64) * 56;
    float* dst = (mode ? wattn : hattn) + ((size_t)b * NC + g * 64) * 56;
    const float* scale = mode ? wsc : hsc;
    const float* bias = mode ? wbi : hbi;
    switch (g) {
        case 0: ph2_work<3>(src, w3, b3, scale, bias, dst, 0,   &S2, t); break;
        case 1: ph2_work<5>(src, w5, b5, scale, bias, dst, 64,  &S2, t); break;
        case 2: ph2_work<7>(src, w7, b7, scale, bias, dst, 128, &S2, t); break;
        default: ph2_work<9>(src, w9, b9, scale, bias, dst, 192, &S2, t); break;
    }
}

// ============ K3: gated 7x7 avgpool -> ypool (all 256 threads in reduce) ============
__global__ __launch_bounds__(256) void k_pool(const float* __restrict__ x,
                                              const float* __restrict__ hattn,
                                              const float* __restrict__ wattn,
                                              float* __restrict__ ypool) {
    int plane = blockIdx.x;
    __shared__ float sm[PLANE];
    __shared__ float ha[56], wa[56];
    const float4* xp = (const float4*)(x + (size_t)plane * PLANE);
    float4* smp = (float4*)sm;
    int t = threadIdx.x;
    for (int f = t; f < PLANE / 4; f += 256) smp[f] = xp[f];
    if (t < 56) ha[t] = hattn[(size_t)plane * 56 + t];
    else if (t >= 64 && t < 120) wa[t - 64] = wattn[(size_t)plane * 56 + (t - 64)];
    __syncthreads();
    int cell = t >> 2, sub = t & 3;      // 64 cells x 4 sub-lanes
    int i = cell >> 3, j = cell & 7;
    float s = 0.f;
#pragma unroll
    for (int k2 = 0; k2 < 2; ++k2) {
        int dh = sub + 4 * k2;
        if (dh < 7) {
            float r = 0.f;
#pragma unroll
            for (int dw = 0; dw < 7; ++dw)
                r += sm[(7 * i + dh) * 56 + 7 * j + dw] * wa[7 * j + dw];
            s += ha[7 * i + dh] * r;
        }
    }
    s += __shfl_xor(s, 1); s += __shfl_xor(s, 2);
    if (sub == 0) ypool[(size_t)plane * NPOOL + cell] = s * (1.f / 49.f);
}

// ============ K4: GN1 stats + tiny attention -> ca, 256 blocks x 256 thr ============
__global__ __launch_bounds__(256) void k_attn(const float* __restrict__ ypool,
                                              const float* __restrict__ nsc,
                                              const float* __restrict__ nbi,
                                              const float* __restrict__ qw,
                                              const float* __restrict__ kw,
                                              const float* __restrict__ vw,
                                              float* __restrict__ ca) {
    int b = blockIdx.x >> 3, h = blockIdx.x & 7;
    int t = threadIdx.x;
    __shared__ float yn[32][65];
    __shared__ float G[32][33];
    __shared__ float ybar[32];
    __shared__ float red[8];
    __shared__ float stats[2];

    const float4* bp4 = (const float4*)(ypool + (size_t)b * NC * NPOOL);
    float s1 = 0.f, s2 = 0.f;
#pragma unroll
    for (int k2 = 0; k2 < 16; ++k2) {
        float4 v = bp4[t + 256 * k2];
        s1 += v.x + v.y + v.z + v.w;
        s2 += v.x * v.x + v.y * v.y + v.z * v.z + v.w * v.w;
    }
#pragma unroll
    for (int off = 32; off >= 1; off >>= 1) {
        s1 += __shfl_xor(s1, off);
        s2 += __shfl_xor(s2, off);
    }
    if ((t & 63) == 0) { red[t >> 6] = s1; red[4 + (t >> 6)] = s2; }
    __syncthreads();
    if (t == 0) {
        float t1 = red[0] + red[1] + red[2] + red[3];
        float t2 = red[4] + red[5] + red[6] + red[7];
        float mean = t1 * (1.f / (NC * NPOOL));
        float var = t2 * (1.f / (NC * NPOOL)) - mean * mean;
        stats[0] = mean; stats[1] = rsqrtf(var + EPSV);
    }
    __syncthreads();
    float mean = stats[0], rstd = stats[1];
    const float* base = ypool + ((size_t)b * NC + h * HDIM) * NPOOL;
#pragma unroll
    for (int m = 0; m < 8; ++m) {
        int idx = t + 256 * m;
        int d = idx >> 6, p = idx & 63;
        int ch = h * HDIM + d;
        yn[d][p] = (base[idx] - mean) * rstd * nsc[ch] + nbi[ch];
    }
    __syncthreads();
    if (t < 32) {
        float s = 0.f;
#pragma unroll
        for (int p = 0; p < 64; ++p) s += yn[t][p];
        ybar[t] = s * (1.f / 64.f);
    }
    __syncthreads();
#pragma unroll
    for (int m = 0; m < 4; ++m) {
        int idx = t + 256 * m;
        int d = idx >> 5, e = idx & 31;
        float s = 0.f;
#pragma unroll
        for (int p = 0; p < 64; ++p) s += yn[d][p] * yn[e][p];
        G[d][e] = s;
    }
    __syncthreads();
    if (t < 32) {
        int d = t, cd = h * HDIM + d;
        float qs = qw[cd] * 0.17677669529663687f;  // 1/sqrt(32)
        float a[32];
        float mx = -1e30f;
#pragma unroll
        for (int e = 0; e < 32; ++e) {
            a[e] = G[d][e] * qs * kw[h * HDIM + e];
            mx = fmaxf(mx, a[e]);
        }
        float sum = 0.f;
#pragma unroll
        for (int e = 0; e < 32; ++e) {
            a[e] = expf(a[e] - mx);
            sum += a[e];
        }
        float o = 0.f;
#pragma unroll
        for (int e = 0; e < 32; ++e) o += a[e] * vw[h * HDIM + e] * ybar[e];
        o /= sum;
        ca[b * NC + cd] = 1.f / (1.f + expf(-o));
    }
}

// ============ K5: out = x * hattn * wattn * ca ============
__global__ __launch_bounds__(256) void k_final(const float* __restrict__ x,
                                               const float* __restrict__ hattn,
                                               const float* __restrict__ wattn,
                                               const float* __restrict__ ca,
                                               float* __restrict__ out) {
    int plane = blockIdx.x;
    __shared__ float hv[56], wv[56];
    int t = threadIdx.x;
    float cav = ca[plane];
    if (t < 56) hv[t] = hattn[(size_t)plane * 56 + t] * cav;
    else if (t >= 64 && t < 120) wv[t - 64] = wattn[(size_t)plane * 56 + (t - 64)];
    __syncthreads();
    const float4* xp = (const float4*)(x + (size_t)plane * PLANE);
    float4* op = (float4*)(out + (size_t)plane * PLANE);
    for (int f = t; f < PLANE / 4; f += 256) {
        int r = f / 14;
        int s0 = (f - r * 14) * 4;
        float4 v = xp[f];
        float hf = hv[r];
        v.x *= hf * wv[s0];
        v.y *= hf * wv[s0 + 1];
        v.z *= hf * wv[s0 + 2];
        v.w *= hf * wv[s0 + 3];
        op[f] = v;
    }
}

extern "C" void kernel_launch(void* const* d_in, const int* in_sizes, int n_in,
                              void* d_out, int out_size, void* d_ws, size_t ws_size,
                              hipStream_t stream) {
    const float* x   = (const float*)d_in[0];
    const float* w3  = (const float*)d_in[1];
    const float* b3  = (const float*)d_in[2];
    const float* w5  = (const float*)d_in[3];
    const float* b5  = (const float*)d_in[4];
    const float* w7  = (const float*)d_in[5];
    const float* b7  = (const float*)d_in[6];
    const float* w9  = (const float*)d_in[7];
    const float* b9  = (const float*)d_in[8];
    const float* hsc = (const float*)d_in[9];
    const float* hbi = (const float*)d_in[10];
    const float* wsc = (const float*)d_in[11];
    const float* wbi = (const float*)d_in[12];
    const float* nsc = (const float*)d_in[13];
    const float* nbi = (const float*)d_in[14];
    const float* qw  = (const float*)d_in[15];
    const float* kw  = (const float*)d_in[16];
    const float* vw  = (const float*)d_in[17];
    float* out = (float*)d_out;

    float* ws    = (float*)d_ws;
    float* hm    = ws;
    float* wm    = hm + (size_t)NPLANE * 56;
    float* hattn = wm + (size_t)NPLANE * 56;
    float* wattn = hattn + (size_t)NPLANE * 56;
    float* ypool = wattn + (size_t)NPLANE * 56;
    float* ca    = ypool + (size_t)NPLANE * NPOOL;

    // Stream-ordered 5-kernel pipeline. Timed path == profiled path; inter-kernel
    // coherence handled by stream dependency (release/acquire per dispatch).
    k_means<<<NPLANE, 256, 0, stream>>>(x, hm, wm);
    k_branch<<<256, 256, 0, stream>>>(hm, wm, w3, b3, w5, b5, w7, b7, w9, b9,
                                      hsc, hbi, wsc, wbi, hattn, wattn);
    k_pool<<<NPLANE, 256, 0, stream>>>(x, hattn, wattn, ypool);
    k_attn<<<NB * NHEADS, 256, 0, stream>>>(ypool, nsc, nbi, qw, kw, vw, ca);
    k_final<<<NPLANE, 256, 0, stream>>>(x, hattn, wattn, ca, out);
}

// Round 10
// 259.634 us; speedup vs baseline: 1.8080x; 1.0027x over previous
//
#include <hip/hip_runtime.h>
#include <cstdint>
#include <cstddef>

#define NB 32        // batch
#define NC 256       // channels
#define HW 56        // spatial
#define PLANE (HW*HW)       // 3136
#define NPLANE (NB*NC)      // 8192
#define NHEADS 8
#define HDIM 32
#define NPOOL 64            // 8*8
#define EPSV 1e-5f

// Native clang vector type: __builtin_nontemporal_store requires scalar or
// ext_vector_type pointers (HIP's float4 is a class and is rejected).
typedef float f32x4 __attribute__((ext_vector_type(4)));

struct Ph2 { float rows[64*57]; float red[8]; };   // 14624 B

// ---- phase 2 worker: depthwise conv (uniform K per block) + GroupNorm(group==block) + sigmoid
// 256 blocks: bid -> mode=bid&1 (h/w), b=(bid>>1)&31, g=bid>>6 (kernel-size group).
template<int K>
__device__ __forceinline__ void ph2_work(const float* __restrict__ src,
                                         const float* __restrict__ wk,
                                         const float* __restrict__ bk,
                                         const float* __restrict__ scale,
                                         const float* __restrict__ bias,
                                         float* __restrict__ dst,
                                         int cbase, Ph2* S2, int t) {
    const float4* sp = (const float4*)src;
#pragma unroll
    for (int k2 = 0; k2 < 4; ++k2) {
        int f = t + 256 * k2;
        if (f < 896) {
            float4 v = sp[f];
            int c = f / 14, r = f - c * 14;
            float* d = &S2->rows[c * 57 + r * 4];
            d[0] = v.x; d[1] = v.y; d[2] = v.z; d[3] = v.w;
        }
    }
    __syncthreads();
    int cc = t >> 2, q = t & 3;          // channel-in-group, quarter of the 56 positions
    float w[K];
#pragma unroll
    for (int j = 0; j < K; ++j) w[j] = wk[cc * K + j];
    float bb = bk[cc];
    const float* row = &S2->rows[cc * 57];
    float y[14];
    float s1 = 0.f, s2 = 0.f;
#pragma unroll
    for (int il = 0; il < 14; ++il) {
        int pos = q * 14 + il;
        float a = bb;
#pragma unroll
        for (int j = 0; j < K; ++j) {
            int p2 = pos + j - K / 2;
            if (p2 >= 0 && p2 < 56) a += w[j] * row[p2];
        }
        y[il] = a; s1 += a; s2 += a * a;
    }
#pragma unroll
    for (int off = 32; off >= 1; off >>= 1) {
        s1 += __shfl_xor(s1, off);
        s2 += __shfl_xor(s2, off);
    }
    int wv = t >> 6;
    if ((t & 63) == 0) { S2->red[wv] = s1; S2->red[4 + wv] = s2; }
    __syncthreads();
    float t1 = S2->red[0] + S2->red[1] + S2->red[2] + S2->red[3];
    float t2 = S2->red[4] + S2->red[5] + S2->red[6] + S2->red[7];
    float mean = t1 * (1.f / 3584.f);
    float var = t2 * (1.f / 3584.f) - mean * mean;
    float rstd = rsqrtf(var + EPSV);
    int c = cbase + cc;
    float scv = scale[c];
    float a_lin = scv * rstd, b_lin = bias[c] - mean * rstd * scv;
#pragma unroll
    for (int il = 0; il < 14; ++il) {
        float v = y[il] * a_lin + b_lin;
        S2->rows[cc * 57 + q * 14 + il] = 1.f / (1.f + expf(-v));
    }
    __syncthreads();
    float4* dp = (float4*)dst;
#pragma unroll
    for (int k2 = 0; k2 < 4; ++k2) {
        int f = t + 256 * k2;
        if (f < 896) {
            int c2 = f / 14, r = f - c2 * 14;
            const float* s = &S2->rows[c2 * 57 + r * 4];
            dp[f] = make_float4(s[0], s[1], s[2], s[3]);
        }
    }
}

// ============ K1: per-plane row/col means ============
__global__ __launch_bounds__(256) void k_means(const float* __restrict__ x,
                                               float* __restrict__ hm,
                                               float* __restrict__ wm) {
    int plane = blockIdx.x;
    __shared__ float sm[PLANE];
    const float4* xp = (const float4*)(x + (size_t)plane * PLANE);
    float4* smp = (float4*)sm;
    int t = threadIdx.x;
    for (int f = t; f < PLANE / 4; f += 256) smp[f] = xp[f];
    __syncthreads();
    if (t < 224) {
        int a = t >> 2, q = t & 3;
        float s = 0.f;
#pragma unroll
        for (int i = 0; i < 14; ++i) s += sm[a * 56 + q * 14 + i];
        s += __shfl_xor(s, 1); s += __shfl_xor(s, 2);
        if (q == 0) hm[(size_t)plane * 56 + a] = s * (1.f / 56.f);
        float s2 = 0.f;
#pragma unroll
        for (int i = 0; i < 14; ++i) s2 += sm[(q * 14 + i) * 56 + a];
        s2 += __shfl_xor(s2, 1); s2 += __shfl_xor(s2, 2);
        if (q == 0) wm[(size_t)plane * 56 + a] = s2 * (1.f / 56.f);
    }
}

// ============ K2: sa_branch (conv + GN4 + sigmoid), 256 blocks ============
__global__ __launch_bounds__(256) void k_branch(
    const float* __restrict__ hm, const float* __restrict__ wm,
    const float* __restrict__ w3, const float* __restrict__ b3,
    const float* __restrict__ w5, const float* __restrict__ b5,
    const float* __restrict__ w7, const float* __restrict__ b7,
    const float* __restrict__ w9, const float* __restrict__ b9,
    const float* __restrict__ hsc, const float* __restrict__ hbi,
    const float* __restrict__ wsc, const float* __restrict__ wbi,
    float* __restrict__ hattn, float* __restrict__ wattn) {
    __shared__ Ph2 S2;
    int t = threadIdx.x, bid = blockIdx.x;
    int mode = bid & 1, b = (bid >> 1) & 31, g = bid >> 6;
    const float* src = (mode ? wm : hm) + ((size_t)b * NC + g * 64) * 56;
    float* dst = (mode ? wattn : hattn) + ((size_t)b * NC + g * 64) * 56;
    const float* scale = mode ? wsc : hsc;
    const float* bias = mode ? wbi : hbi;
    switch (g) {
        case 0: ph2_work<3>(src, w3, b3, scale, bias, dst, 0,   &S2, t); break;
        case 1: ph2_work<5>(src, w5, b5, scale, bias, dst, 64,  &S2, t); break;
        case 2: ph2_work<7>(src, w7, b7, scale, bias, dst, 128, &S2, t); break;
        default: ph2_work<9>(src, w9, b9, scale, bias, dst, 192, &S2, t); break;
    }
}

// ============ K3: gated 7x7 avgpool -> ypool (all 256 threads in reduce) ============
__global__ __launch_bounds__(256) void k_pool(const float* __restrict__ x,
                                              const float* __restrict__ hattn,
                                              const float* __restrict__ wattn,
                                              float* __restrict__ ypool) {
    int plane = blockIdx.x;
    __shared__ float sm[PLANE];
    __shared__ float ha[56], wa[56];
    const float4* xp = (const float4*)(x + (size_t)plane * PLANE);
    float4* smp = (float4*)sm;
    int t = threadIdx.x;
    for (int f = t; f < PLANE / 4; f += 256) smp[f] = xp[f];
    if (t < 56) ha[t] = hattn[(size_t)plane * 56 + t];
    else if (t >= 64 && t < 120) wa[t - 64] = wattn[(size_t)plane * 56 + (t - 64)];
    __syncthreads();
    int cell = t >> 2, sub = t & 3;      // 64 cells x 4 sub-lanes
    int i = cell >> 3, j = cell & 7;
    float s = 0.f;
#pragma unroll
    for (int k2 = 0; k2 < 2; ++k2) {
        int dh = sub + 4 * k2;
        if (dh < 7) {
            float r = 0.f;
#pragma unroll
            for (int dw = 0; dw < 7; ++dw)
                r += sm[(7 * i + dh) * 56 + 7 * j + dw] * wa[7 * j + dw];
            s += ha[7 * i + dh] * r;
        }
    }
    s += __shfl_xor(s, 1); s += __shfl_xor(s, 2);
    if (sub == 0) ypool[(size_t)plane * NPOOL + cell] = s * (1.f / 49.f);
}

// ============ K4: GN1 stats + tiny attention -> ca, 256 blocks x 256 thr ============
__global__ __launch_bounds__(256) void k_attn(const float* __restrict__ ypool,
                                              const float* __restrict__ nsc,
                                              const float* __restrict__ nbi,
                                              const float* __restrict__ qw,
                                              const float* __restrict__ kw,
                                              const float* __restrict__ vw,
                                              float* __restrict__ ca) {
    int b = blockIdx.x >> 3, h = blockIdx.x & 7;
    int t = threadIdx.x;
    __shared__ float yn[32][65];
    __shared__ float G[32][33];
    __shared__ float ybar[32];
    __shared__ float red[8];
    __shared__ float stats[2];

    const float4* bp4 = (const float4*)(ypool + (size_t)b * NC * NPOOL);
    float s1 = 0.f, s2 = 0.f;
#pragma unroll
    for (int k2 = 0; k2 < 16; ++k2) {
        float4 v = bp4[t + 256 * k2];
        s1 += v.x + v.y + v.z + v.w;
        s2 += v.x * v.x + v.y * v.y + v.z * v.z + v.w * v.w;
    }
#pragma unroll
    for (int off = 32; off >= 1; off >>= 1) {
        s1 += __shfl_xor(s1, off);
        s2 += __shfl_xor(s2, off);
    }
    if ((t & 63) == 0) { red[t >> 6] = s1; red[4 + (t >> 6)] = s2; }
    __syncthreads();
    if (t == 0) {
        float t1 = red[0] + red[1] + red[2] + red[3];
        float t2 = red[4] + red[5] + red[6] + red[7];
        float mean = t1 * (1.f / (NC * NPOOL));
        float var = t2 * (1.f / (NC * NPOOL)) - mean * mean;
        stats[0] = mean; stats[1] = rsqrtf(var + EPSV);
    }
    __syncthreads();
    float mean = stats[0], rstd = stats[1];
    const float* base = ypool + ((size_t)b * NC + h * HDIM) * NPOOL;
#pragma unroll
    for (int m = 0; m < 8; ++m) {
        int idx = t + 256 * m;
        int d = idx >> 6, p = idx & 63;
        int ch = h * HDIM + d;
        yn[d][p] = (base[idx] - mean) * rstd * nsc[ch] + nbi[ch];
    }
    __syncthreads();
    if (t < 32) {
        float s = 0.f;
#pragma unroll
        for (int p = 0; p < 64; ++p) s += yn[t][p];
        ybar[t] = s * (1.f / 64.f);
    }
    __syncthreads();
#pragma unroll
    for (int m = 0; m < 4; ++m) {
        int idx = t + 256 * m;
        int d = idx >> 5, e = idx & 31;
        float s = 0.f;
#pragma unroll
        for (int p = 0; p < 64; ++p) s += yn[d][p] * yn[e][p];
        G[d][e] = s;
    }
    __syncthreads();
    if (t < 32) {
        int d = t, cd = h * HDIM + d;
        float qs = qw[cd] * 0.17677669529663687f;  // 1/sqrt(32)
        float a[32];
        float mx = -1e30f;
#pragma unroll
        for (int e = 0; e < 32; ++e) {
            a[e] = G[d][e] * qs * kw[h * HDIM + e];
            mx = fmaxf(mx, a[e]);
        }
        float sum = 0.f;
#pragma unroll
        for (int e = 0; e < 32; ++e) {
            a[e] = expf(a[e] - mx);
            sum += a[e];
        }
        float o = 0.f;
#pragma unroll
        for (int e = 0; e < 32; ++e) o += a[e] * vw[h * HDIM + e] * ybar[e];
        o /= sum;
        ca[b * NC + cd] = 1.f / (1.f + expf(-o));
    }
}

// ============ K5: out = x * hattn * wattn * ca (non-temporal output stores) ============
__global__ __launch_bounds__(256) void k_final(const float* __restrict__ x,
                                               const float* __restrict__ hattn,
                                               const float* __restrict__ wattn,
                                               const float* __restrict__ ca,
                                               float* __restrict__ out) {
    int plane = blockIdx.x;
    __shared__ float hv[56], wv[56];
    int t = threadIdx.x;
    float cav = ca[plane];
    if (t < 56) hv[t] = hattn[(size_t)plane * 56 + t] * cav;
    else if (t >= 64 && t < 120) wv[t - 64] = wattn[(size_t)plane * 56 + (t - 64)];
    __syncthreads();
    const float4* xp = (const float4*)(x + (size_t)plane * PLANE);
    f32x4* op = (f32x4*)(out + (size_t)plane * PLANE);
    for (int f = t; f < PLANE / 4; f += 256) {
        int r = f / 14;
        int s0 = (f - r * 14) * 4;
        float4 v = xp[f];
        float hf = hv[r];
        f32x4 o;
        o.x = v.x * hf * wv[s0];
        o.y = v.y * hf * wv[s0 + 1];
        o.z = v.z * hf * wv[s0 + 2];
        o.w = v.w * hf * wv[s0 + 3];
        // out is write-once, never re-read: non-temporal store avoids the
        // read-for-ownership fetch (~50 MB of wasted HBM reads seen as
        // FETCH_SIZE excess) and LLC pollution; fills show pure-write streams
        // hit 6.9 TB/s with FETCH ~= 0 on this chip. Builtin requires a native
        // ext_vector_type pointer (HIP float4 is a class -> rejected).
        __builtin_nontemporal_store(o, &op[f]);
    }
}

extern "C" void kernel_launch(void* const* d_in, const int* in_sizes, int n_in,
                              void* d_out, int out_size, void* d_ws, size_t ws_size,
                              hipStream_t stream) {
    const float* x   = (const float*)d_in[0];
    const float* w3  = (const float*)d_in[1];
    const float* b3  = (const float*)d_in[2];
    const float* w5  = (const float*)d_in[3];
    const float* b5  = (const float*)d_in[4];
    const float* w7  = (const float*)d_in[5];
    const float* b7  = (const float*)d_in[6];
    const float* w9  = (const float*)d_in[7];
    const float* b9  = (const float*)d_in[8];
    const float* hsc = (const float*)d_in[9];
    const float* hbi = (const float*)d_in[10];
    const float* wsc = (const float*)d_in[11];
    const float* wbi = (const float*)d_in[12];
    const float* nsc = (const float*)d_in[13];
    const float* nbi = (const float*)d_in[14];
    const float* qw  = (const float*)d_in[15];
    const float* kw  = (const float*)d_in[16];
    const float* vw  = (const float*)d_in[17];
    float* out = (float*)d_out;

    float* ws    = (float*)d_ws;
    float* hm    = ws;
    float* wm    = hm + (size_t)NPLANE * 56;
    float* hattn = wm + (size_t)NPLANE * 56;
    float* wattn = hattn + (size_t)NPLANE * 56;
    float* ypool = wattn + (size_t)NPLANE * 56;
    float* ca    = ypool + (size_t)NPLANE * NPOOL;

    // Stream-ordered 5-kernel pipeline. Timed path == profiled path; inter-kernel
    // coherence handled by stream dependency (release/acquire per dispatch).
    k_means<<<NPLANE, 256, 0, stream>>>(x, hm, wm);
    k_branch<<<256, 256, 0, stream>>>(hm, wm, w3, b3, w5, b5, w7, b7, w9, b9,
                                      hsc, hbi, wsc, wbi, hattn, wattn);
    k_pool<<<NPLANE, 256, 0, stream>>>(x, hattn, wattn, ypool);
    k_attn<<<NB * NHEADS, 256, 0, stream>>>(ypool, nsc, nbi, qw, kw, vw, ca);
    k_final<<<NPLANE, 256, 0, stream>>>(x, hattn, wattn, ca, out);
}